// Round 1
// baseline (793.481 us; speedup 1.0000x reference)
//
#include <hip/hip_runtime.h>
#include <math.h>

#define B_ 8
#define C_ 64
#define H_ 160
#define W_ 160
#define G_ 4
#define CG 16      // C/G
#define CQ 8       // q/k channels
#define HW_ (H_*W_)
#define TW 8       // phase-2 tile width (query positions per tile)

static constexpr size_t N_PIX  = (size_t)B_*H_*W_;       // 204800
static constexpr size_t N_FULL = (size_t)B_*H_*W_*C_;    // 13107200
// ws layout (floats):
//   [0, N_FULL)            outH   [b][h][w][c]  (unnormalized H-attention output)
//   [N_FULL, +N_PIX)       mH     [b][w][h]
//   [.., +N_PIX)           sH     [b][w][h]
//   [OFF_O, +N_FULL)       xT / o (aliased: xT consumed by passA; o produced by passB)
//   then bnsum[64], bnsq[64], scale[64], shift[64]
static constexpr size_t OFF_MH    = N_FULL;
static constexpr size_t OFF_SH    = OFF_MH + N_PIX;
static constexpr size_t OFF_O     = OFF_SH + N_PIX;
static constexpr size_t OFF_BNSUM = OFF_O + N_FULL;
static constexpr size_t OFF_BNSQ  = OFF_BNSUM + 64;
static constexpr size_t OFF_SCALE = OFF_BNSQ + 64;
static constexpr size_t OFF_SHIFT = OFF_SCALE + 64;
// total = 26,624,256 floats ~= 101.6 MiB

// ---- x (NCHW) -> xT [b][w][h][c]  (so passA column loads are coalesced) ----
__global__ __launch_bounds__(256) void transpose_kernel(const float* __restrict__ x,
                                                        float* __restrict__ xT)
{
    __shared__ float t[64*129];   // pad 129 so strided-c reads hit distinct banks
    const int tid = threadIdx.x;
    const int w0 = blockIdx.x * 32;
    const int h0 = blockIdx.y * 4;
    const int b  = blockIdx.z;
    const float* xb = x + (size_t)b*C_*HW_;
    for (int i = tid; i < 64*4*32; i += 256) {
        int c = i >> 7;          // i/128
        int h = (i >> 5) & 3;
        int w = i & 31;
        t[c*129 + h*32 + w] = xb[(size_t)c*HW_ + (h0+h)*W_ + (w0+w)];
    }
    __syncthreads();
    float* xTb = xT + (size_t)b*HW_*64;
    for (int i = tid; i < 64*4*32; i += 256) {
        int c   = i & 63;
        int pix = i >> 6;        // 0..127
        int w   = pix & 31;
        int h   = pix >> 5;
        xTb[((size_t)(w0+w)*H_ + (h0+h))*64 + c] = t[c*129 + h*32 + w];
    }
}

// ---- pass A: per (b,w) column — H-direction attention (diag masked) ----
__global__ __launch_bounds__(256) void passA_kernel(
    const float* __restrict__ xT,
    const float* __restrict__ wq, const float* __restrict__ bq,
    const float* __restrict__ wk, const float* __restrict__ bk,
    const float* __restrict__ wv, const float* __restrict__ bv,
    float* __restrict__ outH, float* __restrict__ mH, float* __restrict__ sH)
{
    __shared__ float xcol[H_][65];    // x column, later overwritten by v column
    __shared__ float qc[H_][CQ];
    __shared__ float kc[H_][CQ];
    __shared__ float Pt[H_][TW];
    __shared__ float mArr[H_];
    __shared__ float wqs[CG][CQ], wks[CG][CQ];
    __shared__ float wvs[CG][C_];
    __shared__ float bqs[CQ], bks[CQ], bvs[C_];

    const int tid = threadIdx.x;
    const int b = blockIdx.x / W_;
    const int w = blockIdx.x % W_;

    for (int i = tid; i < CQ*CG; i += 256) {
        int cq = i / CG, ci = i % CG;
        wqs[ci][cq] = wq[i]; wks[ci][cq] = wk[i];
    }
    for (int i = tid; i < C_*CG; i += 256) wvs[i % CG][i / CG] = wv[i];
    if (tid < CQ) { bqs[tid] = bq[tid]; bks[tid] = bk[tid]; }
    if (tid >= 64 && tid < 128) bvs[tid-64] = bv[tid-64];

    const float* xcp = xT + ((size_t)b*W_ + w)*H_*64;
    for (int i = tid; i < H_*64; i += 256) xcol[i >> 6][i & 63] = xcp[i];
    __syncthreads();

    // q, k for the whole column
    for (int i = tid; i < H_*CQ; i += 256) {
        int j = i >> 3, cq = i & 7;
        int g = cq >> 1;                       // Cq/G = 2
        float aq = bqs[cq], ak = bks[cq];
        #pragma unroll
        for (int ci = 0; ci < CG; ci++) {
            float xv = xcol[j][g*CG + ci];
            aq += xv * wqs[ci][cq];
            ak += xv * wks[ci][cq];
        }
        qc[j][cq] = aq; kc[j][cq] = ak;
    }
    // v column into registers, then overwrite xcol in place
    float vreg[40];
    {
        const int c = tid & 63, j0 = tid >> 6;
        const int g = c >> 4;
        #pragma unroll
        for (int i = 0; i < 40; i++) {
            int j = j0 + i*4;
            float a = bvs[c];
            #pragma unroll
            for (int ci = 0; ci < CG; ci++) a += xcol[j][g*CG + ci] * wvs[ci][c];
            vreg[i] = a;
        }
    }
    __syncthreads();
    {
        const int c = tid & 63, j0 = tid >> 6;
        #pragma unroll
        for (int i = 0; i < 40; i++) xcol[j0 + i*4][c] = vreg[i];
    }
    __syncthreads();

    // phase 1: online softmax stats per query h (diag excluded)
    if (tid < H_) {
        const int h = tid;
        float qreg[CQ];
        #pragma unroll
        for (int cq = 0; cq < CQ; cq++) qreg[cq] = qc[h][cq];
        float m = -INFINITY, s = 0.f;
        for (int j = 0; j < H_; j++) {
            if (j == h) continue;
            float e = 0.f;
            #pragma unroll
            for (int cq = 0; cq < CQ; cq++) e += qreg[cq] * kc[j][cq];
            if (e > m) { s = s * __expf(m - e) + 1.f; m = e; }
            else         s += __expf(e - m);
        }
        mArr[h] = m;
        mH[((size_t)b*W_ + w)*H_ + h] = m;
        sH[((size_t)b*W_ + w)*H_ + h] = s;
    }
    __syncthreads();

    // phase 2: P tiles + accumulate out_H~
    const int c = tid & 63;
    const int hh0 = (tid >> 6) * 2;
    for (int t = 0; t < H_/TW; t++) {
        for (int i = tid; i < H_*TW; i += 256) {
            int j = i >> 3, hh = i & 7;
            int h = t*TW + hh;
            float e = 0.f;
            #pragma unroll
            for (int cq = 0; cq < CQ; cq++) e += qc[h][cq] * kc[j][cq];
            Pt[j][hh] = (j == h) ? 0.f : __expf(e - mArr[h]);
        }
        __syncthreads();
        float acc0 = 0.f, acc1 = 0.f;
        #pragma unroll 4
        for (int j = 0; j < H_; j++) {
            float vv = xcol[j][c];
            const float2 p = *(const float2*)&Pt[j][hh0];
            acc0 += p.x * vv;
            acc1 += p.y * vv;
        }
        const int h0 = t*TW + hh0;
        float* op = outH + (((size_t)b*H_ + h0)*W_ + w)*64 + c;
        op[0]             = acc0;
        op[(size_t)W_*64] = acc1;
        __syncthreads();
    }
}

// ---- pass B: per (b,h) row — W-direction attention + merge + w1d conv + BN partials ----
__global__ __launch_bounds__(256) void passB_kernel(
    const float* __restrict__ x,
    const float* __restrict__ wq, const float* __restrict__ bq,
    const float* __restrict__ wk, const float* __restrict__ bk,
    const float* __restrict__ wv, const float* __restrict__ bv,
    const float* __restrict__ gamma, const float* __restrict__ w1d,
    const float* __restrict__ outH, const float* __restrict__ mH, const float* __restrict__ sH,
    float* __restrict__ o_ws, float* __restrict__ bnsum, float* __restrict__ bnsq)
{
    __shared__ float xrow[W_][65];    // x row -> v row in place
    __shared__ float qr[W_][CQ];
    __shared__ float kr[W_][CQ];
    __shared__ float Pt[W_][TW];      // reused as stage[TW][64] for the conv
    __shared__ float mWArr[W_], fHs[W_], fWs[W_];
    __shared__ float wqs[CG][CQ], wks[CG][CQ];
    __shared__ float wUs[CG][C_];     // wv first, then reloaded with w1d
    __shared__ float bqs[CQ], bks[CQ], bvs[C_];

    const int tid = threadIdx.x;
    const int b = blockIdx.x / H_;
    const int h = blockIdx.x % H_;
    const float gam = gamma[0];

    for (int i = tid; i < CQ*CG; i += 256) {
        int cq = i / CG, ci = i % CG;
        wqs[ci][cq] = wq[i]; wks[ci][cq] = wk[i];
    }
    for (int i = tid; i < C_*CG; i += 256) wUs[i % CG][i / CG] = wv[i];
    if (tid < CQ) { bqs[tid] = bq[tid]; bks[tid] = bk[tid]; }
    if (tid >= 64 && tid < 128) bvs[tid-64] = bv[tid-64];

    const float* xb = x + (size_t)b*C_*HW_ + (size_t)h*W_;
    for (int i = tid; i < C_*W_; i += 256) {
        int c = i / W_, j = i % W_;
        xrow[j][c] = xb[(size_t)c*HW_ + j];
    }
    __syncthreads();

    for (int i = tid; i < W_*CQ; i += 256) {
        int j = i >> 3, cq = i & 7;
        int g = cq >> 1;
        float aq = bqs[cq], ak = bks[cq];
        #pragma unroll
        for (int ci = 0; ci < CG; ci++) {
            float xv = xrow[j][g*CG + ci];
            aq += xv * wqs[ci][cq];
            ak += xv * wks[ci][cq];
        }
        qr[j][cq] = aq; kr[j][cq] = ak;
    }
    float vreg[40];
    {
        const int c = tid & 63, j0 = tid >> 6;
        const int g = c >> 4;
        #pragma unroll
        for (int i = 0; i < 40; i++) {
            int j = j0 + i*4;
            float a = bvs[c];
            #pragma unroll
            for (int ci = 0; ci < CG; ci++) a += xrow[j][g*CG + ci] * wUs[ci][c];
            vreg[i] = a;
        }
    }
    __syncthreads();
    {
        const int c = tid & 63, j0 = tid >> 6;
        #pragma unroll
        for (int i = 0; i < 40; i++) xrow[j0 + i*4][c] = vreg[i];
    }
    // wv reads all happened before the barrier above -> safe to reload with w1d
    for (int i = tid; i < C_*CG; i += 256) wUs[i % CG][i / CG] = w1d[i];
    __syncthreads();

    // phase 1: W-direction stats + merge factors with H-direction (gamma folded in)
    if (tid < W_) {
        const int w = tid;
        float qreg[CQ];
        #pragma unroll
        for (int cq = 0; cq < CQ; cq++) qreg[cq] = qr[w][cq];
        float m = -INFINITY, s = 0.f;
        for (int j = 0; j < W_; j++) {
            float e = 0.f;
            #pragma unroll
            for (int cq = 0; cq < CQ; cq++) e += qreg[cq] * kr[j][cq];
            if (e > m) { s = s * __expf(m - e) + 1.f; m = e; }
            else         s += __expf(e - m);
        }
        float mHv = mH[((size_t)b*W_ + w)*H_ + h];
        float sHv = sH[((size_t)b*W_ + w)*H_ + h];
        float M  = fmaxf(mHv, m);
        float eH = __expf(mHv - M), eW = __expf(m - M);
        float inv = gam / (sHv*eH + s*eW);
        mWArr[w] = m;
        fHs[w] = eH * inv;
        fWs[w] = eW * inv;
    }
    __syncthreads();

    const int c = tid & 63;
    const int ww0 = (tid >> 6) * 2;
    const int g = c >> 4;
    float bnS = 0.f, bnS2 = 0.f;
    for (int t = 0; t < W_/TW; t++) {
        for (int i = tid; i < W_*TW; i += 256) {
            int j = i >> 3, ww = i & 7;
            int w = t*TW + ww;
            float e = 0.f;
            #pragma unroll
            for (int cq = 0; cq < CQ; cq++) e += qr[w][cq] * kr[j][cq];
            Pt[j][ww] = __expf(e - mWArr[w]);
        }
        __syncthreads();
        float a0 = 0.f, a1 = 0.f;
        #pragma unroll 4
        for (int j = 0; j < W_; j++) {
            float vv = xrow[j][c];
            const float2 p = *(const float2*)&Pt[j][ww0];
            a0 += p.x * vv;
            a1 += p.y * vv;
        }
        const int w0 = t*TW + ww0;
        const float* ohp = outH + (((size_t)b*H_ + h)*W_ + w0)*64 + c;
        float comb0 = ohp[0]  * fHs[w0]   + a0 * fWs[w0];
        float comb1 = ohp[64] * fHs[w0+1] + a1 * fWs[w0+1];
        __syncthreads();                       // Pt reads done -> reuse as stage
        float* stage = &Pt[0][0];
        stage[ww0*64 + c]     = comb0;
        stage[(ww0+1)*64 + c] = comb1;
        __syncthreads();
        float o0 = 0.f, o1 = 0.f;
        #pragma unroll
        for (int ci = 0; ci < CG; ci++) {
            float wgt = wUs[ci][c];
            o0 += stage[ww0*64     + g*CG + ci] * wgt;
            o1 += stage[(ww0+1)*64 + g*CG + ci] * wgt;
        }
        float* op = o_ws + (((size_t)b*H_ + h)*W_ + w0)*64 + c;
        op[0]  = o0;
        op[64] = o1;
        bnS  += o0 + o1;
        bnS2 += o0*o0 + o1*o1;
        __syncthreads();                       // before next tile overwrites Pt
    }
    // per-block BN reduction (reuse qr/kr as scratch), one atomic per channel
    float* redA = &qr[0][0];
    float* redB = &kr[0][0];
    redA[tid] = bnS;
    redB[tid] = bnS2;
    __syncthreads();
    if (tid < 64) {
        float s1 = redA[tid] + redA[tid+64] + redA[tid+128] + redA[tid+192];
        float s2 = redB[tid] + redB[tid+64] + redB[tid+128] + redB[tid+192];
        atomicAdd(&bnsum[tid], s1);
        atomicAdd(&bnsq[tid],  s2);
    }
}

// ---- BN finalize: per-channel scale/shift ----
__global__ void bnfin_kernel(const float* __restrict__ sum, const float* __restrict__ sq,
                             const float* __restrict__ bn_w, const float* __restrict__ bn_b,
                             float* __restrict__ scale, float* __restrict__ shift)
{
    int c = threadIdx.x;
    if (c < C_) {
        const float cnt = (float)(B_*H_*W_);
        float mean = sum[c] / cnt;
        float var  = sq[c] / cnt - mean*mean;
        float istd = rsqrtf(var + 1e-5f);
        float scl  = bn_w[c] * istd;
        scale[c] = scl;
        shift[c] = bn_b[c] - mean*scl;
    }
}

// ---- final: normalize + residual + relu, pixel-major -> NCHW via LDS ----
__global__ __launch_bounds__(256) void final_kernel(
    const float* __restrict__ x, const float* __restrict__ o_ws,
    const float* __restrict__ scale, const float* __restrict__ shift,
    float* __restrict__ out)
{
    __shared__ float olds[W_][65];
    __shared__ float sc[C_], sh[C_];
    const int tid = threadIdx.x;
    const int b = blockIdx.x / H_, h = blockIdx.x % H_;
    if (tid < C_) { sc[tid] = scale[tid]; sh[tid] = shift[tid]; }
    const float* op = o_ws + ((size_t)b*H_ + h)*W_*64;
    for (int i = tid; i < W_*64; i += 256) olds[i >> 6][i & 63] = op[i];
    __syncthreads();
    const float* xb = x  + (size_t)b*C_*HW_ + (size_t)h*W_;
    float*       ob = out + (size_t)b*C_*HW_ + (size_t)h*W_;
    for (int i = tid; i < C_*W_; i += 256) {
        int c = i / W_, w = i % W_;
        float v = olds[w][c] * sc[c] + sh[c] + xb[(size_t)c*HW_ + w];
        ob[(size_t)c*HW_ + w] = fmaxf(v, 0.f);
    }
}

extern "C" void kernel_launch(void* const* d_in, const int* in_sizes, int n_in,
                              void* d_out, int out_size, void* d_ws, size_t ws_size,
                              hipStream_t stream)
{
    (void)in_sizes; (void)n_in; (void)out_size; (void)ws_size;
    const float* x     = (const float*)d_in[0];
    const float* wq    = (const float*)d_in[1];
    const float* bq    = (const float*)d_in[2];
    const float* wk    = (const float*)d_in[3];
    const float* bk    = (const float*)d_in[4];
    const float* wv    = (const float*)d_in[5];
    const float* bv    = (const float*)d_in[6];
    const float* gamma = (const float*)d_in[7];
    const float* w1d   = (const float*)d_in[8];
    const float* bn_w  = (const float*)d_in[9];
    const float* bn_b  = (const float*)d_in[10];

    float* ws    = (float*)d_ws;
    float* outH  = ws;
    float* mH    = ws + OFF_MH;
    float* sH    = ws + OFF_SH;
    float* xT_o  = ws + OFF_O;       // xT (passA input) aliases o (passB output)
    float* bnsum = ws + OFF_BNSUM;
    float* bnsq  = ws + OFF_BNSQ;
    float* scale = ws + OFF_SCALE;
    float* shift = ws + OFF_SHIFT;

    hipMemsetAsync(bnsum, 0, 128*sizeof(float), stream);   // bnsum + bnsq

    dim3 tgrid(W_/32, H_/4, B_);
    transpose_kernel<<<tgrid, 256, 0, stream>>>(x, xT_o);
    passA_kernel<<<B_*W_, 256, 0, stream>>>(xT_o, wq, bq, wk, bk, wv, bv, outH, mH, sH);
    passB_kernel<<<B_*H_, 256, 0, stream>>>(x, wq, bq, wk, bk, wv, bv, gamma, w1d,
                                            outH, mH, sH, xT_o /* now o */, bnsum, bnsq);
    bnfin_kernel<<<1, 64, 0, stream>>>(bnsum, bnsq, bn_w, bn_b, scale, shift);
    final_kernel<<<B_*H_, 256, 0, stream>>>(x, xT_o /* o */, scale, shift, (float*)d_out);
}

// Round 3
// 290.754 us; speedup vs baseline: 2.7291x; 2.7291x over previous
//
#include <hip/hip_runtime.h>
#include <math.h>

#define B_ 8
#define C_ 64
#define H_ 160
#define W_ 160
#define HW_ (H_*W_)

typedef _Float16 h2 __attribute__((ext_vector_type(2)));
typedef _Float16 h8 __attribute__((ext_vector_type(8)));
typedef float f4v __attribute__((ext_vector_type(4)));

static constexpr size_t N_PIX  = (size_t)B_*H_*W_;       // 204800
static constexpr size_t N_FULL = (size_t)B_*H_*W_*C_;    // 13107200
// ws (floats): outH | mH | sH | xT/o (aliased) | bnsum[64] bnsq[64] scale[64] shift[64]
static constexpr size_t OFF_MH    = N_FULL;
static constexpr size_t OFF_SH    = OFF_MH + N_PIX;
static constexpr size_t OFF_O     = OFF_SH + N_PIX;
static constexpr size_t OFF_BNSUM = OFF_O + N_FULL;
static constexpr size_t OFF_BNSQ  = OFF_BNSUM + 64;
static constexpr size_t OFF_SCALE = OFF_BNSQ + 64;
static constexpr size_t OFF_SHIFT = OFF_SCALE + 64;

// ---- x (NCHW) -> xT [b][w][h][c] fp32 ----
__global__ __launch_bounds__(256) void transpose_kernel(const float* __restrict__ x,
                                                        float* __restrict__ xT)
{
    __shared__ float t[64*129];
    const int tid = threadIdx.x;
    const int w0 = blockIdx.x * 32;
    const int h0 = blockIdx.y * 4;
    const int b  = blockIdx.z;
    const float* xb = x + (size_t)b*C_*HW_;
    for (int i = tid; i < 64*4*32; i += 256) {
        int c = i >> 7;
        int h = (i >> 5) & 3;
        int w = i & 31;
        t[c*129 + h*32 + w] = xb[(size_t)c*HW_ + (h0+h)*W_ + (w0+w)];
    }
    __syncthreads();
    float* xTb = xT + (size_t)b*HW_*64;
    for (int i = tid; i < 64*4*32; i += 256) {
        int c   = i & 63;
        int pix = i >> 6;
        int w   = pix & 31;
        int h   = pix >> 5;
        xTb[((size_t)(w0+w)*H_ + (h0+h))*64 + c] = t[c*129 + h*32 + w];
    }
}

// ---- pass A: per (b,w) column — H-attention (diag masked) ----
// fp32 q/k/energies/exp; P,V stored f16; P·V via MFMA 16x16x32 f16.
__global__ __launch_bounds__(256,2) void passA_kernel(
    const float* __restrict__ xT,
    const float* __restrict__ wq, const float* __restrict__ bq,
    const float* __restrict__ wk, const float* __restrict__ bk,
    const float* __restrict__ wv, const float* __restrict__ bv,
    float* __restrict__ outH, float* __restrict__ mH, float* __restrict__ sH)
{
    __shared__ __align__(16) char ureg[23040];     // xs[160][36] f32  |  Pt[32][84] h2
    __shared__ __align__(16) h2 v2[64][84];        // vT[c][j-pairs], stride 336B
    __shared__ __align__(16) float q2[160][12];
    __shared__ __align__(16) float k2[160][12];

    float (*xs)[36] = (float(*)[36])ureg;
    h2 (*Pt)[84]    = (h2(*)[84])ureg;

    const int tid = threadIdx.x;
    const int b = blockIdx.x / W_;
    const int w = blockIdx.x % W_;
    const float* xcol = xT + ((size_t)b*W_ + w)*H_*64;

    for (int hh = 0; hh < 2; hh++) {
        // stage channels [32hh, 32hh+32) of the column (fp32)
        for (int i = tid; i < 160*8; i += 256) {
            int h = i >> 3, c4 = (i & 7) * 4;
            *(float4*)&xs[h][c4] = *(const float4*)(xcol + (size_t)h*64 + 32*hh + c4);
        }
        __syncthreads();
        // q/k for cq in [4hh, 4hh+4)
        {
            const int cql = tid & 3;
            const int cq  = 4*hh + cql;
            const int gl  = cql >> 1;     // local group (0/1)
            float wqr[16], wkr[16];
            #pragma unroll
            for (int p = 0; p < 4; p++) {
                *(float4*)&wqr[4*p] = ((const float4*)(wq + cq*16))[p];
                *(float4*)&wkr[4*p] = ((const float4*)(wk + cq*16))[p];
            }
            const float bqv = bq[cq], bkv = bk[cq];
            for (int i = tid; i < 640; i += 256) {
                int j = i >> 2;
                const float4* xr = (const float4*)&xs[j][16*gl];
                float aq = bqv, ak = bkv;
                #pragma unroll
                for (int p = 0; p < 4; p++) {
                    float4 xv = xr[p];
                    aq += xv.x*wqr[4*p] + xv.y*wqr[4*p+1] + xv.z*wqr[4*p+2] + xv.w*wqr[4*p+3];
                    ak += xv.x*wkr[4*p] + xv.y*wkr[4*p+1] + xv.z*wkr[4*p+2] + xv.w*wkr[4*p+3];
                }
                q2[j][cq] = aq; k2[j][cq] = ak;
            }
        }
        // v for c in [32hh, 32hh+32): fp32 compute, f16 store (j-pairs)
        {
            const int cl = tid & 31, jq = tid >> 5;
            const int c  = 32*hh + cl;
            const int gl = cl >> 4;
            float wvr[16];
            #pragma unroll
            for (int p = 0; p < 4; p++) *(float4*)&wvr[4*p] = ((const float4*)(wv + c*16))[p];
            const float bvv = bv[c];
            #pragma unroll 2
            for (int it = 0; it < 10; it++) {
                int j0 = it*16 + 2*jq;
                const float4* xr0 = (const float4*)&xs[j0][16*gl];
                const float4* xr1 = (const float4*)&xs[j0+1][16*gl];
                float a0 = bvv, a1 = bvv;
                #pragma unroll
                for (int p = 0; p < 4; p++) {
                    float4 x0 = xr0[p], x1 = xr1[p];
                    a0 += x0.x*wvr[4*p] + x0.y*wvr[4*p+1] + x0.z*wvr[4*p+2] + x0.w*wvr[4*p+3];
                    a1 += x1.x*wvr[4*p] + x1.y*wvr[4*p+1] + x1.z*wvr[4*p+2] + x1.w*wvr[4*p+3];
                }
                h2 vv; vv.x = (_Float16)a0; vv.y = (_Float16)a1;
                v2[c][8*it + jq] = vv;
            }
        }
        __syncthreads();
    }

    const int u    = tid & 7;
    const int wl   = tid >> 3;
    const int lane = tid & 63;
    const int wid  = tid >> 6;
    const int cM   = wid*16 + (lane & 15);
    const int m_   = lane & 15;
    const int dq   = lane >> 4;

    for (int t = 0; t < 5; t++) {
        // energies (fp32, once) + stats via shuffle + P (f16)
        const int qh = t*32 + wl;
        float qr[8];
        *(float4*)&qr[0] = *(const float4*)&q2[qh][0];
        *(float4*)&qr[4] = *(const float4*)&q2[qh][4];
        float ev[20];
        float mloc = -1e30f;
        #pragma unroll
        for (int p = 0; p < 10; p++) {
            int j0 = 2*(u + 8*p);
            const float4 ka = *(const float4*)&k2[j0][0];
            const float4 kb = *(const float4*)&k2[j0][4];
            const float4 kc = *(const float4*)&k2[j0+1][0];
            const float4 kd = *(const float4*)&k2[j0+1][4];
            float e0 = qr[0]*ka.x + qr[1]*ka.y + qr[2]*ka.z + qr[3]*ka.w
                     + qr[4]*kb.x + qr[5]*kb.y + qr[6]*kb.z + qr[7]*kb.w;
            float e1 = qr[0]*kc.x + qr[1]*kc.y + qr[2]*kc.z + qr[3]*kc.w
                     + qr[4]*kd.x + qr[5]*kd.y + qr[6]*kd.z + qr[7]*kd.w;
            ev[2*p] = e0; ev[2*p+1] = e1;
            if (j0   != qh) mloc = fmaxf(mloc, e0);
            if (j0+1 != qh) mloc = fmaxf(mloc, e1);
        }
        mloc = fmaxf(mloc, __shfl_xor(mloc, 1));
        mloc = fmaxf(mloc, __shfl_xor(mloc, 2));
        mloc = fmaxf(mloc, __shfl_xor(mloc, 4));
        float sloc = 0.f;
        #pragma unroll
        for (int p = 0; p < 10; p++) {
            int j0 = 2*(u + 8*p);
            float p0 = (j0   == qh) ? 0.f : __expf(ev[2*p]   - mloc);
            float p1 = (j0+1 == qh) ? 0.f : __expf(ev[2*p+1] - mloc);
            sloc += p0 + p1;
            h2 pp; pp.x = (_Float16)p0; pp.y = (_Float16)p1;
            Pt[wl][u + 8*p] = pp;
        }
        sloc += __shfl_xor(sloc, 1);
        sloc += __shfl_xor(sloc, 2);
        sloc += __shfl_xor(sloc, 4);
        if (u == 0) {
            mH[((size_t)b*W_ + w)*H_ + qh] = mloc;
            sH[((size_t)b*W_ + w)*H_ + qh] = sloc;
        }
        __syncthreads();

        // P·V via MFMA: M=32 (queries), N=64 (c), K=160 (j)
        f4v acc0 = {0.f,0.f,0.f,0.f}, acc1 = {0.f,0.f,0.f,0.f};
        #pragma unroll
        for (int kt = 0; kt < 5; kt++) {
            const int off = 64*kt + 16*dq;
            h8 bfr = *(const h8*)((const char*)&v2[cM][0] + off);
            h8 a0  = *(const h8*)((const char*)&Pt[m_][0] + off);
            h8 a1  = *(const h8*)((const char*)&Pt[16 + m_][0] + off);
            acc0 = __builtin_amdgcn_mfma_f32_16x16x32_f16(a0, bfr, acc0, 0, 0, 0);
            acc1 = __builtin_amdgcn_mfma_f32_16x16x32_f16(a1, bfr, acc1, 0, 0, 0);
        }
        #pragma unroll
        for (int r = 0; r < 4; r++) {
            int r0 = t*32 + dq*4 + r;       // C/D: col=lane&15, row=(lane>>4)*4+reg
            outH[(((size_t)b*H_ + r0     )*W_ + w)*64 + cM] = acc0[r];
            outH[(((size_t)b*H_ + r0 + 16)*W_ + w)*64 + cM] = acc1[r];
        }
        __syncthreads();
    }
}

// ---- pass B: per (b,h) row — W-attention + merge + w1d conv + BN partials ----
__global__ __launch_bounds__(256,2) void passB_kernel(
    const float* __restrict__ x,
    const float* __restrict__ wq, const float* __restrict__ bq,
    const float* __restrict__ wk, const float* __restrict__ bk,
    const float* __restrict__ wv, const float* __restrict__ bv,
    const float* __restrict__ gamma, const float* __restrict__ w1d,
    const float* __restrict__ outH, const float* __restrict__ mH, const float* __restrict__ sH,
    float* __restrict__ o_ws, float* __restrict__ bnsum, float* __restrict__ bnsq)
{
    __shared__ __align__(16) char ureg[23040];     // xs[160][36] f32 | Pt[32][84] h2 + stage[32][68] f32 @12288
    __shared__ __align__(16) h2 v2[64][84];
    __shared__ __align__(16) float q2[160][12];
    __shared__ __align__(16) float k2[160][12];
    __shared__ float fHs[32], fWs[32];

    float (*xs)[36]    = (float(*)[36])ureg;
    h2 (*Pt)[84]       = (h2(*)[84])ureg;
    float (*stage)[68] = (float(*)[68])(ureg + 12288);

    const int tid = threadIdx.x;
    const int b = blockIdx.x / H_;
    const int h = blockIdx.x % H_;
    const float gam = gamma[0];

    const int lane = tid & 63;
    const int wid  = tid >> 6;
    const int cM   = wid*16 + (lane & 15);
    const int m_   = lane & 15;
    const int dq   = lane >> 4;

    float w1dr[16];
    #pragma unroll
    for (int p = 0; p < 4; p++) *(float4*)&w1dr[4*p] = ((const float4*)(w1d + cM*16))[p];

    const float* xb = x + (size_t)b*C_*HW_ + (size_t)h*W_;

    for (int hh = 0; hh < 2; hh++) {
        for (int i = tid; i < 5120; i += 256) {
            int cl = i / 160;
            int j  = i - cl*160;
            xs[j][cl] = xb[(size_t)(32*hh + cl)*HW_ + j];
        }
        __syncthreads();
        {
            const int cql = tid & 3;
            const int cq  = 4*hh + cql;
            const int gl  = cql >> 1;
            float wqr[16], wkr[16];
            #pragma unroll
            for (int p = 0; p < 4; p++) {
                *(float4*)&wqr[4*p] = ((const float4*)(wq + cq*16))[p];
                *(float4*)&wkr[4*p] = ((const float4*)(wk + cq*16))[p];
            }
            const float bqv = bq[cq], bkv = bk[cq];
            for (int i = tid; i < 640; i += 256) {
                int j = i >> 2;
                const float4* xr = (const float4*)&xs[j][16*gl];
                float aq = bqv, ak = bkv;
                #pragma unroll
                for (int p = 0; p < 4; p++) {
                    float4 xv = xr[p];
                    aq += xv.x*wqr[4*p] + xv.y*wqr[4*p+1] + xv.z*wqr[4*p+2] + xv.w*wqr[4*p+3];
                    ak += xv.x*wkr[4*p] + xv.y*wkr[4*p+1] + xv.z*wkr[4*p+2] + xv.w*wkr[4*p+3];
                }
                q2[j][cq] = aq; k2[j][cq] = ak;
            }
        }
        {
            const int cl = tid & 31, jq = tid >> 5;
            const int c  = 32*hh + cl;
            const int gl = cl >> 4;
            float wvr[16];
            #pragma unroll
            for (int p = 0; p < 4; p++) *(float4*)&wvr[4*p] = ((const float4*)(wv + c*16))[p];
            const float bvv = bv[c];
            #pragma unroll 2
            for (int it = 0; it < 10; it++) {
                int j0 = it*16 + 2*jq;
                const float4* xr0 = (const float4*)&xs[j0][16*gl];
                const float4* xr1 = (const float4*)&xs[j0+1][16*gl];
                float a0 = bvv, a1 = bvv;
                #pragma unroll
                for (int p = 0; p < 4; p++) {
                    float4 x0 = xr0[p], x1 = xr1[p];
                    a0 += x0.x*wvr[4*p] + x0.y*wvr[4*p+1] + x0.z*wvr[4*p+2] + x0.w*wvr[4*p+3];
                    a1 += x1.x*wvr[4*p] + x1.y*wvr[4*p+1] + x1.z*wvr[4*p+2] + x1.w*wvr[4*p+3];
                }
                h2 vv; vv.x = (_Float16)a0; vv.y = (_Float16)a1;
                v2[c][8*it + jq] = vv;
            }
        }
        __syncthreads();
    }

    const int u  = tid & 7;
    const int wl = tid >> 3;
    float bnS = 0.f, bnS2 = 0.f;

    for (int t = 0; t < 5; t++) {
        const int qw = t*32 + wl;            // query = w coordinate
        float qr[8];
        *(float4*)&qr[0] = *(const float4*)&q2[qw][0];
        *(float4*)&qr[4] = *(const float4*)&q2[qw][4];
        float ev[20];
        float mloc = -1e30f;
        #pragma unroll
        for (int p = 0; p < 10; p++) {
            int j0 = 2*(u + 8*p);
            const float4 ka = *(const float4*)&k2[j0][0];
            const float4 kb = *(const float4*)&k2[j0][4];
            const float4 kc = *(const float4*)&k2[j0+1][0];
            const float4 kd = *(const float4*)&k2[j0+1][4];
            float e0 = qr[0]*ka.x + qr[1]*ka.y + qr[2]*ka.z + qr[3]*ka.w
                     + qr[4]*kb.x + qr[5]*kb.y + qr[6]*kb.z + qr[7]*kb.w;
            float e1 = qr[0]*kc.x + qr[1]*kc.y + qr[2]*kc.z + qr[3]*kc.w
                     + qr[4]*kd.x + qr[5]*kd.y + qr[6]*kd.z + qr[7]*kd.w;
            ev[2*p] = e0; ev[2*p+1] = e1;
            mloc = fmaxf(mloc, e0);
            mloc = fmaxf(mloc, e1);
        }
        mloc = fmaxf(mloc, __shfl_xor(mloc, 1));
        mloc = fmaxf(mloc, __shfl_xor(mloc, 2));
        mloc = fmaxf(mloc, __shfl_xor(mloc, 4));
        float sloc = 0.f;
        #pragma unroll
        for (int p = 0; p < 10; p++) {
            float p0 = __expf(ev[2*p]   - mloc);
            float p1 = __expf(ev[2*p+1] - mloc);
            sloc += p0 + p1;
            h2 pp; pp.x = (_Float16)p0; pp.y = (_Float16)p1;
            Pt[wl][u + 8*p] = pp;
        }
        sloc += __shfl_xor(sloc, 1);
        sloc += __shfl_xor(sloc, 2);
        sloc += __shfl_xor(sloc, 4);
        if (u == 0) {
            float mHv = mH[((size_t)b*W_ + qw)*H_ + h];
            float sHv = sH[((size_t)b*W_ + qw)*H_ + h];
            float M   = fmaxf(mHv, mloc);
            float eH  = __expf(mHv - M), eW = __expf(mloc - M);
            float inv = gam / (sHv*eH + sloc*eW);
            fHs[wl] = eH * inv;
            fWs[wl] = eW * inv;
        }
        __syncthreads();

        // P_W · V via MFMA
        f4v acc0 = {0.f,0.f,0.f,0.f}, acc1 = {0.f,0.f,0.f,0.f};
        #pragma unroll
        for (int kt = 0; kt < 5; kt++) {
            const int off = 64*kt + 16*dq;
            h8 bfr = *(const h8*)((const char*)&v2[cM][0] + off);
            h8 a0  = *(const h8*)((const char*)&Pt[m_][0] + off);
            h8 a1  = *(const h8*)((const char*)&Pt[16 + m_][0] + off);
            acc0 = __builtin_amdgcn_mfma_f32_16x16x32_f16(a0, bfr, acc0, 0, 0, 0);
            acc1 = __builtin_amdgcn_mfma_f32_16x16x32_f16(a1, bfr, acc1, 0, 0, 0);
        }
        // merge with H branch (gamma folded into fHs/fWs), stage fp32 (within-wave)
        #pragma unroll
        for (int r = 0; r < 4; r++) {
            int rl0 = dq*4 + r, rl1 = rl0 + 16;
            int rw0 = t*32 + rl0, rw1 = t*32 + rl1;
            float oh0 = outH[(((size_t)b*H_ + h)*W_ + rw0)*64 + cM];
            float oh1 = outH[(((size_t)b*H_ + h)*W_ + rw1)*64 + cM];
            stage[rl0][cM] = oh0*fHs[rl0] + acc0[r]*fWs[rl0];
            stage[rl1][cM] = oh1*fHs[rl1] + acc1[r]*fWs[rl1];
        }
        // grouped w1d conv: wave `wid` owns out-channels 16wid..16wid+15 = group wid,
        // whose inputs are exactly the cols this wave just wrote (same-wave LDS, no barrier)
        #pragma unroll
        for (int r = 0; r < 4; r++) {
            #pragma unroll
            for (int mt = 0; mt < 2; mt++) {
                int rl = dq*4 + r + 16*mt;
                int rw = t*32 + rl;
                const float4* sp = (const float4*)&stage[rl][16*wid];
                float o = 0.f;
                #pragma unroll
                for (int p = 0; p < 4; p++) {
                    float4 sv = sp[p];
                    o += sv.x*w1dr[4*p] + sv.y*w1dr[4*p+1] + sv.z*w1dr[4*p+2] + sv.w*w1dr[4*p+3];
                }
                o_ws[(((size_t)b*H_ + h)*W_ + rw)*64 + cM] = o;
                bnS  += o;
                bnS2 += o*o;
            }
        }
        __syncthreads();
    }
    // BN partials: reduce over the 4 lane-quads holding the same channel
    bnS  += __shfl_xor(bnS, 16);  bnS  += __shfl_xor(bnS, 32);
    bnS2 += __shfl_xor(bnS2, 16); bnS2 += __shfl_xor(bnS2, 32);
    if (dq == 0) {
        atomicAdd(&bnsum[cM], bnS);
        atomicAdd(&bnsq[cM],  bnS2);
    }
}

// ---- BN finalize ----
__global__ void bnfin_kernel(const float* __restrict__ sum, const float* __restrict__ sq,
                             const float* __restrict__ bn_w, const float* __restrict__ bn_b,
                             float* __restrict__ scale, float* __restrict__ shift)
{
    int c = threadIdx.x;
    if (c < C_) {
        const float cnt = (float)(B_*H_*W_);
        float mean = sum[c] / cnt;
        float var  = sq[c] / cnt - mean*mean;
        float istd = rsqrtf(var + 1e-5f);
        float scl  = bn_w[c] * istd;
        scale[c] = scl;
        shift[c] = bn_b[c] - mean*scl;
    }
}

// ---- final: normalize + residual + relu, pixel-major -> NCHW ----
__global__ __launch_bounds__(256) void final_kernel(
    const float* __restrict__ x, const float* __restrict__ o_ws,
    const float* __restrict__ scale, const float* __restrict__ shift,
    float* __restrict__ out)
{
    __shared__ float olds[W_][65];
    __shared__ float sc[C_], sh[C_];
    const int tid = threadIdx.x;
    const int b = blockIdx.x / H_, h = blockIdx.x % H_;
    if (tid < C_) { sc[tid] = scale[tid]; sh[tid] = shift[tid]; }
    const float* op = o_ws + ((size_t)b*H_ + h)*W_*64;
    for (int i = tid; i < W_*64; i += 256) olds[i >> 6][i & 63] = op[i];
    __syncthreads();
    const float* xr = x   + (size_t)b*C_*HW_ + (size_t)h*W_;
    float*       ob = out + (size_t)b*C_*HW_ + (size_t)h*W_;
    for (int i = tid; i < C_*W_; i += 256) {
        int c = i / W_, w = i - c*W_;
        float v = olds[w][c] * sc[c] + sh[c] + xr[(size_t)c*HW_ + w];
        ob[(size_t)c*HW_ + w] = fmaxf(v, 0.f);
    }
}

extern "C" void kernel_launch(void* const* d_in, const int* in_sizes, int n_in,
                              void* d_out, int out_size, void* d_ws, size_t ws_size,
                              hipStream_t stream)
{
    (void)in_sizes; (void)n_in; (void)out_size; (void)ws_size;
    const float* x     = (const float*)d_in[0];
    const float* wq    = (const float*)d_in[1];
    const float* bq    = (const float*)d_in[2];
    const float* wk    = (const float*)d_in[3];
    const float* bk    = (const float*)d_in[4];
    const float* wv    = (const float*)d_in[5];
    const float* bv    = (const float*)d_in[6];
    const float* gamma = (const float*)d_in[7];
    const float* w1d   = (const float*)d_in[8];
    const float* bn_w  = (const float*)d_in[9];
    const float* bn_b  = (const float*)d_in[10];

    float* ws    = (float*)d_ws;
    float* outH  = ws;
    float* mH    = ws + OFF_MH;
    float* sH    = ws + OFF_SH;
    float* xT_o  = ws + OFF_O;       // xT (passA input) aliases o (passB output)
    float* bnsum = ws + OFF_BNSUM;
    float* bnsq  = ws + OFF_BNSQ;
    float* scale = ws + OFF_SCALE;
    float* shift = ws + OFF_SHIFT;

    hipMemsetAsync(bnsum, 0, 128*sizeof(float), stream);

    dim3 tgrid(W_/32, H_/4, B_);
    transpose_kernel<<<tgrid, 256, 0, stream>>>(x, xT_o);
    passA_kernel<<<B_*W_, 256, 0, stream>>>(xT_o, wq, bq, wk, bk, wv, bv, outH, mH, sH);
    passB_kernel<<<B_*H_, 256, 0, stream>>>(x, wq, bq, wk, bk, wv, bv, gamma, w1d,
                                            outH, mH, sH, xT_o /* now o */, bnsum, bnsq);
    bnfin_kernel<<<1, 64, 0, stream>>>(bnsum, bnsq, bn_w, bn_b, scale, shift);
    final_kernel<<<B_*H_, 256, 0, stream>>>(x, xT_o /* o */, scale, shift, (float*)d_out);
}

// Round 4
// 268.091 us; speedup vs baseline: 2.9597x; 1.0845x over previous
//
#include <hip/hip_runtime.h>
#include <math.h>

#define B_ 8
#define C_ 64
#define H_ 160
#define W_ 160
#define HW_ (H_*W_)

typedef _Float16 h2 __attribute__((ext_vector_type(2)));
typedef _Float16 h8 __attribute__((ext_vector_type(8)));
typedef float f4v __attribute__((ext_vector_type(4)));
union H8u { h8 v; h2 h[4]; };

__device__ inline float fdot2(h2 a, h2 b, float c) {
    return __builtin_amdgcn_fdot2(a, b, c, false);
}

static constexpr size_t N_PIX  = (size_t)B_*H_*W_;       // 204800
static constexpr size_t N_FULL = (size_t)B_*H_*W_*C_;    // 13107200
// ws (floats): outH | mH | sH | xT/o (aliased) | bnsum[64] bnsq[64] scale[64] shift[64]
static constexpr size_t OFF_MH    = N_FULL;
static constexpr size_t OFF_SH    = OFF_MH + N_PIX;
static constexpr size_t OFF_O     = OFF_SH + N_PIX;
static constexpr size_t OFF_BNSUM = OFF_O + N_FULL;
static constexpr size_t OFF_BNSQ  = OFF_BNSUM + 64;
static constexpr size_t OFF_SCALE = OFF_BNSQ + 64;
static constexpr size_t OFF_SHIFT = OFF_SCALE + 64;

// ---- x (NCHW) -> xT [b][w][h][c] fp32 ----
__global__ __launch_bounds__(256) void transpose_kernel(const float* __restrict__ x,
                                                        float* __restrict__ xT)
{
    __shared__ float t[64*129];
    const int tid = threadIdx.x;
    const int w0 = blockIdx.x * 32;
    const int h0 = blockIdx.y * 4;
    const int b  = blockIdx.z;
    const float* xb = x + (size_t)b*C_*HW_;
    for (int i = tid; i < 64*4*32; i += 256) {
        int c = i >> 7;
        int h = (i >> 5) & 3;
        int w = i & 31;
        t[c*129 + h*32 + w] = xb[(size_t)c*HW_ + (h0+h)*W_ + (w0+w)];
    }
    __syncthreads();
    float* xTb = xT + (size_t)b*HW_*64;
    for (int i = tid; i < 64*4*32; i += 256) {
        int c   = i & 63;
        int pix = i >> 6;
        int w   = pix & 31;
        int h   = pix >> 5;
        xTb[((size_t)(w0+w)*H_ + (h0+h))*64 + c] = t[c*129 + h*32 + w];
    }
}

// ---- pass A: per (b,w) column — H-attention (diag masked) ----
// fp32 x/weights/energy-accum/exp; q,k,P,V stored f16; P·V via MFMA 16x16x32 f16.
__global__ __launch_bounds__(256,3) void passA_kernel(
    const float* __restrict__ xT,
    const float* __restrict__ wq, const float* __restrict__ bq,
    const float* __restrict__ wk, const float* __restrict__ bk,
    const float* __restrict__ wv, const float* __restrict__ bv,
    float* __restrict__ outH, float* __restrict__ mH, float* __restrict__ sH)
{
    __shared__ __align__(16) char ureg[23040];     // xs[160][36] f32  |  Pt dbuf: 2 x h2[32][84]
    __shared__ __align__(16) h2 v2[64][84];        // vT[c][j-pairs], row 336B
    __shared__ __align__(16) _Float16 q2h[160][8];
    __shared__ __align__(16) _Float16 k2h[160][8];

    float (*xs)[36] = (float(*)[36])ureg;

    const int tid = threadIdx.x;
    const int b = blockIdx.x / W_;
    const int w = blockIdx.x % W_;
    const float* xcol = xT + ((size_t)b*W_ + w)*H_*64;

    for (int hh = 0; hh < 2; hh++) {
        // stage channels [32hh, 32hh+32) of the column (fp32)
        for (int i = tid; i < 160*8; i += 256) {
            int h = i >> 3, c4 = (i & 7) * 4;
            *(float4*)&xs[h][c4] = *(const float4*)(xcol + (size_t)h*64 + 32*hh + c4);
        }
        __syncthreads();
        // q/k for cq in [4hh, 4hh+4): fp32 compute, f16 store
        {
            const int cql = tid & 3;
            const int cq  = 4*hh + cql;
            const int gl  = cql >> 1;     // local group (0/1)
            float wqr[16], wkr[16];
            #pragma unroll
            for (int p = 0; p < 4; p++) {
                *(float4*)&wqr[4*p] = ((const float4*)(wq + cq*16))[p];
                *(float4*)&wkr[4*p] = ((const float4*)(wk + cq*16))[p];
            }
            const float bqv = bq[cq], bkv = bk[cq];
            for (int i = tid; i < 640; i += 256) {
                int j = i >> 2;
                const float4* xr = (const float4*)&xs[j][16*gl];
                float aq = bqv, ak = bkv;
                #pragma unroll
                for (int p = 0; p < 4; p++) {
                    float4 xv = xr[p];
                    aq += xv.x*wqr[4*p] + xv.y*wqr[4*p+1] + xv.z*wqr[4*p+2] + xv.w*wqr[4*p+3];
                    ak += xv.x*wkr[4*p] + xv.y*wkr[4*p+1] + xv.z*wkr[4*p+2] + xv.w*wkr[4*p+3];
                }
                q2h[j][cq] = (_Float16)aq;
                k2h[j][cq] = (_Float16)ak;
            }
        }
        // v for c in [32hh, 32hh+32): fp32 compute, f16 store (j-pairs)
        {
            const int cl = tid & 31, jq = tid >> 5;
            const int c  = 32*hh + cl;
            const int gl = cl >> 4;
            float wvr[16];
            #pragma unroll
            for (int p = 0; p < 4; p++) *(float4*)&wvr[4*p] = ((const float4*)(wv + c*16))[p];
            const float bvv = bv[c];
            #pragma unroll 2
            for (int it = 0; it < 10; it++) {
                int j0 = it*16 + 2*jq;
                const float4* xr0 = (const float4*)&xs[j0][16*gl];
                const float4* xr1 = (const float4*)&xs[j0+1][16*gl];
                float a0 = bvv, a1 = bvv;
                #pragma unroll
                for (int p = 0; p < 4; p++) {
                    float4 x0 = xr0[p], x1 = xr1[p];
                    a0 += x0.x*wvr[4*p] + x0.y*wvr[4*p+1] + x0.z*wvr[4*p+2] + x0.w*wvr[4*p+3];
                    a1 += x1.x*wvr[4*p] + x1.y*wvr[4*p+1] + x1.z*wvr[4*p+2] + x1.w*wvr[4*p+3];
                }
                h2 vv; vv.x = (_Float16)a0; vv.y = (_Float16)a1;
                v2[c][8*it + jq] = vv;
            }
        }
        __syncthreads();
    }

    const int u    = tid & 7;
    const int wl   = tid >> 3;
    const int lane = tid & 63;
    const int wid  = tid >> 6;
    const int cM   = wid*16 + (lane & 15);
    const int m_   = lane & 15;
    const int dq   = lane >> 4;

    for (int t = 0; t < 5; t++) {
        h2 (*Pt)[84] = (h2(*)[84])(ureg + (t & 1)*10752);   // double-buffered
        // energies (fp32 accum via dot2) + stats via shuffle + P (f16)
        const int qh = t*32 + wl;
        H8u qr; qr.v = *(const h8*)&q2h[qh][0];
        float ev[20];
        float mloc = -1e30f;
        #pragma unroll 2
        for (int p = 0; p < 10; p++) {
            int j0 = 2*(u + 8*p);
            H8u ka; ka.v = *(const h8*)&k2h[j0][0];
            H8u kb; kb.v = *(const h8*)&k2h[j0+1][0];
            float e0 = 0.f, e1 = 0.f;
            #pragma unroll
            for (int i = 0; i < 4; i++) {
                e0 = fdot2(qr.h[i], ka.h[i], e0);
                e1 = fdot2(qr.h[i], kb.h[i], e1);
            }
            ev[2*p] = e0; ev[2*p+1] = e1;
            if (j0   != qh) mloc = fmaxf(mloc, e0);
            if (j0+1 != qh) mloc = fmaxf(mloc, e1);
        }
        mloc = fmaxf(mloc, __shfl_xor(mloc, 1));
        mloc = fmaxf(mloc, __shfl_xor(mloc, 2));
        mloc = fmaxf(mloc, __shfl_xor(mloc, 4));
        float sloc = 0.f;
        #pragma unroll
        for (int p = 0; p < 10; p++) {
            int j0 = 2*(u + 8*p);
            float p0 = (j0   == qh) ? 0.f : __expf(ev[2*p]   - mloc);
            float p1 = (j0+1 == qh) ? 0.f : __expf(ev[2*p+1] - mloc);
            sloc += p0 + p1;
            h2 pp; pp.x = (_Float16)p0; pp.y = (_Float16)p1;
            Pt[wl][u + 8*p] = pp;
        }
        sloc += __shfl_xor(sloc, 1);
        sloc += __shfl_xor(sloc, 2);
        sloc += __shfl_xor(sloc, 4);
        if (u == 0) {
            mH[((size_t)b*W_ + w)*H_ + qh] = mloc;
            sH[((size_t)b*W_ + w)*H_ + qh] = sloc;
        }
        __syncthreads();

        // P·V via MFMA: M=32 (queries), N=64 (c), K=160 (j)
        f4v acc0 = {0.f,0.f,0.f,0.f}, acc1 = {0.f,0.f,0.f,0.f};
        #pragma unroll
        for (int kt = 0; kt < 5; kt++) {
            const int off = 64*kt + 16*dq;
            h8 bfr = *(const h8*)((const char*)&v2[cM][0] + off);
            h8 a0  = *(const h8*)((const char*)&Pt[m_][0] + off);
            h8 a1  = *(const h8*)((const char*)&Pt[16 + m_][0] + off);
            acc0 = __builtin_amdgcn_mfma_f32_16x16x32_f16(a0, bfr, acc0, 0, 0, 0);
            acc1 = __builtin_amdgcn_mfma_f32_16x16x32_f16(a1, bfr, acc1, 0, 0, 0);
        }
        #pragma unroll
        for (int r = 0; r < 4; r++) {
            int r0 = t*32 + dq*4 + r;       // C/D: col=lane&15, row=(lane>>4)*4+reg
            outH[(((size_t)b*H_ + r0     )*W_ + w)*64 + cM] = acc0[r];
            outH[(((size_t)b*H_ + r0 + 16)*W_ + w)*64 + cM] = acc1[r];
        }
        // no trailing barrier: Pt is double-buffered; next tile's barrier orders reuse
    }
}

// ---- pass B: per (b,h) row — W-attention + merge + w1d conv + BN partials ----
__global__ __launch_bounds__(256,3) void passB_kernel(
    const float* __restrict__ x,
    const float* __restrict__ wq, const float* __restrict__ bq,
    const float* __restrict__ wk, const float* __restrict__ bk,
    const float* __restrict__ wv, const float* __restrict__ bv,
    const float* __restrict__ gamma, const float* __restrict__ w1d,
    const float* __restrict__ outH, const float* __restrict__ mH, const float* __restrict__ sH,
    float* __restrict__ o_ws, float* __restrict__ bnsum, float* __restrict__ bnsq)
{
    __shared__ __align__(16) char ureg[23040];     // xs[160][36] f32 | Pt[32][84] h2 + stage[32][68] f32 @12288
    __shared__ __align__(16) h2 v2[64][84];
    __shared__ __align__(16) _Float16 q2h[160][8];
    __shared__ __align__(16) _Float16 k2h[160][8];
    __shared__ float fHs[32], fWs[32];

    float (*xs)[36]    = (float(*)[36])ureg;
    h2 (*Pt)[84]       = (h2(*)[84])ureg;
    float (*stage)[68] = (float(*)[68])(ureg + 12288);

    const int tid = threadIdx.x;
    const int b = blockIdx.x / H_;
    const int h = blockIdx.x % H_;
    const float gam = gamma[0];

    const int lane = tid & 63;
    const int wid  = tid >> 6;
    const int cM   = wid*16 + (lane & 15);
    const int m_   = lane & 15;
    const int dq   = lane >> 4;

    float w1dr[16];
    #pragma unroll
    for (int p = 0; p < 4; p++) *(float4*)&w1dr[4*p] = ((const float4*)(w1d + cM*16))[p];

    const float* xb = x + (size_t)b*C_*HW_ + (size_t)h*W_;

    for (int hh = 0; hh < 2; hh++) {
        for (int i = tid; i < 5120; i += 256) {
            int cl = i / 160;
            int j  = i - cl*160;
            xs[j][cl] = xb[(size_t)(32*hh + cl)*HW_ + j];
        }
        __syncthreads();
        {
            const int cql = tid & 3;
            const int cq  = 4*hh + cql;
            const int gl  = cql >> 1;
            float wqr[16], wkr[16];
            #pragma unroll
            for (int p = 0; p < 4; p++) {
                *(float4*)&wqr[4*p] = ((const float4*)(wq + cq*16))[p];
                *(float4*)&wkr[4*p] = ((const float4*)(wk + cq*16))[p];
            }
            const float bqv = bq[cq], bkv = bk[cq];
            for (int i = tid; i < 640; i += 256) {
                int j = i >> 2;
                const float4* xr = (const float4*)&xs[j][16*gl];
                float aq = bqv, ak = bkv;
                #pragma unroll
                for (int p = 0; p < 4; p++) {
                    float4 xv = xr[p];
                    aq += xv.x*wqr[4*p] + xv.y*wqr[4*p+1] + xv.z*wqr[4*p+2] + xv.w*wqr[4*p+3];
                    ak += xv.x*wkr[4*p] + xv.y*wkr[4*p+1] + xv.z*wkr[4*p+2] + xv.w*wkr[4*p+3];
                }
                q2h[j][cq] = (_Float16)aq;
                k2h[j][cq] = (_Float16)ak;
            }
        }
        {
            const int cl = tid & 31, jq = tid >> 5;
            const int c  = 32*hh + cl;
            const int gl = cl >> 4;
            float wvr[16];
            #pragma unroll
            for (int p = 0; p < 4; p++) *(float4*)&wvr[4*p] = ((const float4*)(wv + c*16))[p];
            const float bvv = bv[c];
            #pragma unroll 2
            for (int it = 0; it < 10; it++) {
                int j0 = it*16 + 2*jq;
                const float4* xr0 = (const float4*)&xs[j0][16*gl];
                const float4* xr1 = (const float4*)&xs[j0+1][16*gl];
                float a0 = bvv, a1 = bvv;
                #pragma unroll
                for (int p = 0; p < 4; p++) {
                    float4 x0 = xr0[p], x1 = xr1[p];
                    a0 += x0.x*wvr[4*p] + x0.y*wvr[4*p+1] + x0.z*wvr[4*p+2] + x0.w*wvr[4*p+3];
                    a1 += x1.x*wvr[4*p] + x1.y*wvr[4*p+1] + x1.z*wvr[4*p+2] + x1.w*wvr[4*p+3];
                }
                h2 vv; vv.x = (_Float16)a0; vv.y = (_Float16)a1;
                v2[c][8*it + jq] = vv;
            }
        }
        __syncthreads();
    }

    const int u  = tid & 7;
    const int wl = tid >> 3;
    float bnS = 0.f, bnS2 = 0.f;

    for (int t = 0; t < 5; t++) {
        // prefetch outH for this tile (used after the MFMA) — covered by energy phase
        float oh0[4], oh1[4];
        #pragma unroll
        for (int r = 0; r < 4; r++) {
            int rw0 = t*32 + dq*4 + r;
            oh0[r] = outH[(((size_t)b*H_ + h)*W_ + rw0     )*64 + cM];
            oh1[r] = outH[(((size_t)b*H_ + h)*W_ + rw0 + 16)*64 + cM];
        }

        const int qw = t*32 + wl;            // query = w coordinate
        H8u qr; qr.v = *(const h8*)&q2h[qw][0];
        float ev[20];
        float mloc = -1e30f;
        #pragma unroll 2
        for (int p = 0; p < 10; p++) {
            int j0 = 2*(u + 8*p);
            H8u ka; ka.v = *(const h8*)&k2h[j0][0];
            H8u kb; kb.v = *(const h8*)&k2h[j0+1][0];
            float e0 = 0.f, e1 = 0.f;
            #pragma unroll
            for (int i = 0; i < 4; i++) {
                e0 = fdot2(qr.h[i], ka.h[i], e0);
                e1 = fdot2(qr.h[i], kb.h[i], e1);
            }
            ev[2*p] = e0; ev[2*p+1] = e1;
            mloc = fmaxf(mloc, e0);
            mloc = fmaxf(mloc, e1);
        }
        mloc = fmaxf(mloc, __shfl_xor(mloc, 1));
        mloc = fmaxf(mloc, __shfl_xor(mloc, 2));
        mloc = fmaxf(mloc, __shfl_xor(mloc, 4));
        float sloc = 0.f;
        #pragma unroll
        for (int p = 0; p < 10; p++) {
            float p0 = __expf(ev[2*p]   - mloc);
            float p1 = __expf(ev[2*p+1] - mloc);
            sloc += p0 + p1;
            h2 pp; pp.x = (_Float16)p0; pp.y = (_Float16)p1;
            Pt[wl][u + 8*p] = pp;
        }
        sloc += __shfl_xor(sloc, 1);
        sloc += __shfl_xor(sloc, 2);
        sloc += __shfl_xor(sloc, 4);
        if (u == 0) {
            float mHv = mH[((size_t)b*W_ + qw)*H_ + h];
            float sHv = sH[((size_t)b*W_ + qw)*H_ + h];
            float M   = fmaxf(mHv, mloc);
            float eH  = __expf(mHv - M), eW = __expf(mloc - M);
            float inv = gam / (sHv*eH + sloc*eW);
            fHs[wl] = eH * inv;
            fWs[wl] = eW * inv;
        }
        __syncthreads();

        // P_W · V via MFMA
        f4v acc0 = {0.f,0.f,0.f,0.f}, acc1 = {0.f,0.f,0.f,0.f};
        #pragma unroll
        for (int kt = 0; kt < 5; kt++) {
            const int off = 64*kt + 16*dq;
            h8 bfr = *(const h8*)((const char*)&v2[cM][0] + off);
            h8 a0  = *(const h8*)((const char*)&Pt[m_][0] + off);
            h8 a1  = *(const h8*)((const char*)&Pt[16 + m_][0] + off);
            acc0 = __builtin_amdgcn_mfma_f32_16x16x32_f16(a0, bfr, acc0, 0, 0, 0);
            acc1 = __builtin_amdgcn_mfma_f32_16x16x32_f16(a1, bfr, acc1, 0, 0, 0);
        }
        // merge with H branch (gamma folded into fHs/fWs), stage fp32 (within-wave)
        #pragma unroll
        for (int r = 0; r < 4; r++) {
            int rl0 = dq*4 + r, rl1 = rl0 + 16;
            stage[rl0][cM] = oh0[r]*fHs[rl0] + acc0[r]*fWs[rl0];
            stage[rl1][cM] = oh1[r]*fHs[rl1] + acc1[r]*fWs[rl1];
        }
        // grouped w1d conv: wave `wid` owns out-channels 16wid..16wid+15 = group wid,
        // whose inputs are exactly the cols this wave just wrote (same-wave LDS, no barrier)
        #pragma unroll
        for (int r = 0; r < 4; r++) {
            #pragma unroll
            for (int mt = 0; mt < 2; mt++) {
                int rl = dq*4 + r + 16*mt;
                int rw = t*32 + rl;
                const float4* sp = (const float4*)&stage[rl][16*wid];
                float o = 0.f;
                #pragma unroll
                for (int p = 0; p < 4; p++) {
                    float4 sv = sp[p];
                    o += sv.x*w1dr[4*p] + sv.y*w1dr[4*p+1] + sv.z*w1dr[4*p+2] + sv.w*w1dr[4*p+3];
                }
                o_ws[(((size_t)b*H_ + h)*W_ + rw)*64 + cM] = o;
                bnS  += o;
                bnS2 += o*o;
            }
        }
        __syncthreads();
    }
    // BN partials: reduce over the 4 lane-quads holding the same channel
    bnS  += __shfl_xor(bnS, 16);  bnS  += __shfl_xor(bnS, 32);
    bnS2 += __shfl_xor(bnS2, 16); bnS2 += __shfl_xor(bnS2, 32);
    if (dq == 0) {
        atomicAdd(&bnsum[cM], bnS);
        atomicAdd(&bnsq[cM],  bnS2);
    }
}

// ---- BN finalize ----
__global__ void bnfin_kernel(const float* __restrict__ sum, const float* __restrict__ sq,
                             const float* __restrict__ bn_w, const float* __restrict__ bn_b,
                             float* __restrict__ scale, float* __restrict__ shift)
{
    int c = threadIdx.x;
    if (c < C_) {
        const float cnt = (float)(B_*H_*W_);
        float mean = sum[c] / cnt;
        float var  = sq[c] / cnt - mean*mean;
        float istd = rsqrtf(var + 1e-5f);
        float scl  = bn_w[c] * istd;
        scale[c] = scl;
        shift[c] = bn_b[c] - mean*scl;
    }
}

// ---- final: normalize + residual + relu, pixel-major -> NCHW ----
__global__ __launch_bounds__(256) void final_kernel(
    const float* __restrict__ x, const float* __restrict__ o_ws,
    const float* __restrict__ scale, const float* __restrict__ shift,
    float* __restrict__ out)
{
    __shared__ float olds[W_][65];
    __shared__ float sc[C_], sh[C_];
    const int tid = threadIdx.x;
    const int b = blockIdx.x / H_, h = blockIdx.x % H_;
    if (tid < C_) { sc[tid] = scale[tid]; sh[tid] = shift[tid]; }
    const float* op = o_ws + ((size_t)b*H_ + h)*W_*64;
    for (int i = tid; i < W_*64; i += 256) olds[i >> 6][i & 63] = op[i];
    __syncthreads();
    const float* xr = x   + (size_t)b*C_*HW_ + (size_t)h*W_;
    float*       ob = out + (size_t)b*C_*HW_ + (size_t)h*W_;
    for (int i = tid; i < C_*W_; i += 256) {
        int c = i / W_, w = i - c*W_;
        float v = olds[w][c] * sc[c] + sh[c] + xr[(size_t)c*HW_ + w];
        ob[(size_t)c*HW_ + w] = fmaxf(v, 0.f);
    }
}

extern "C" void kernel_launch(void* const* d_in, const int* in_sizes, int n_in,
                              void* d_out, int out_size, void* d_ws, size_t ws_size,
                              hipStream_t stream)
{
    (void)in_sizes; (void)n_in; (void)out_size; (void)ws_size;
    const float* x     = (const float*)d_in[0];
    const float* wq    = (const float*)d_in[1];
    const float* bq    = (const float*)d_in[2];
    const float* wk    = (const float*)d_in[3];
    const float* bk    = (const float*)d_in[4];
    const float* wv    = (const float*)d_in[5];
    const float* bv    = (const float*)d_in[6];
    const float* gamma = (const float*)d_in[7];
    const float* w1d   = (const float*)d_in[8];
    const float* bn_w  = (const float*)d_in[9];
    const float* bn_b  = (const float*)d_in[10];

    float* ws    = (float*)d_ws;
    float* outH  = ws;
    float* mH    = ws + OFF_MH;
    float* sH    = ws + OFF_SH;
    float* xT_o  = ws + OFF_O;       // xT (passA input) aliases o (passB output)
    float* bnsum = ws + OFF_BNSUM;
    float* bnsq  = ws + OFF_BNSQ;
    float* scale = ws + OFF_SCALE;
    float* shift = ws + OFF_SHIFT;

    hipMemsetAsync(bnsum, 0, 128*sizeof(float), stream);

    dim3 tgrid(W_/32, H_/4, B_);
    transpose_kernel<<<tgrid, 256, 0, stream>>>(x, xT_o);
    passA_kernel<<<B_*W_, 256, 0, stream>>>(xT_o, wq, bq, wk, bk, wv, bv, outH, mH, sH);
    passB_kernel<<<B_*H_, 256, 0, stream>>>(x, wq, bq, wk, bk, wv, bv, gamma, w1d,
                                            outH, mH, sH, xT_o /* now o */, bnsum, bnsq);
    bnfin_kernel<<<1, 64, 0, stream>>>(bnsum, bnsq, bn_w, bn_b, scale, shift);
    final_kernel<<<B_*H_, 256, 0, stream>>>(x, xT_o /* o */, scale, shift, (float*)d_out);
}

// Round 5
// 252.533 us; speedup vs baseline: 3.1421x; 1.0616x over previous
//
#include <hip/hip_runtime.h>
#include <math.h>

#define B_ 8
#define C_ 64
#define H_ 160
#define W_ 160
#define HW_ (H_*W_)

typedef _Float16 h2 __attribute__((ext_vector_type(2)));
typedef _Float16 h8 __attribute__((ext_vector_type(8)));
typedef float f4v __attribute__((ext_vector_type(4)));
union H8u { h8 v; h2 h[4]; };

__device__ inline float fdot2(h2 a, h2 b, float c) {
    return __builtin_amdgcn_fdot2(a, b, c, false);
}
__device__ inline float dot16(const float4* xr, const float* wr, float acc) {
    float4 a = xr[0], b = xr[1], c = xr[2], d = xr[3];
    acc += a.x*wr[0]  + a.y*wr[1]  + a.z*wr[2]  + a.w*wr[3];
    acc += b.x*wr[4]  + b.y*wr[5]  + b.z*wr[6]  + b.w*wr[7];
    acc += c.x*wr[8]  + c.y*wr[9]  + c.z*wr[10] + c.w*wr[11];
    acc += d.x*wr[12] + d.y*wr[13] + d.z*wr[14] + d.w*wr[15];
    return acc;
}

static constexpr size_t N_PIX  = (size_t)B_*H_*W_;       // 204800
static constexpr size_t N_FULL = (size_t)B_*H_*W_*C_;    // 13107200
// ws (float units):
static constexpr size_t OFF_OUTH  = 0;                       // outH f16 [b][h][w][c] (N_FULL/2 fl)
static constexpr size_t OFF_VROW  = N_FULL/2;                // v_row f16 [b][h][w][c]; o16 aliases
static constexpr size_t OFF_QROW  = OFF_VROW + N_FULL/2;     // q_row f16 [b][h][w][8]
static constexpr size_t OFF_KROW  = OFF_QROW + N_PIX*4;
static constexpr size_t OFF_MH    = OFF_KROW + N_PIX*4;      // fp32 [b][w][h]
static constexpr size_t OFF_SH    = OFF_MH + N_PIX;
static constexpr size_t OFF_BNSUM = OFF_SH + N_PIX;
static constexpr size_t OFF_BNSQ  = OFF_BNSUM + 64;
static constexpr size_t OFF_SCALE = OFF_BNSQ + 64;
static constexpr size_t OFF_SHIFT = OFF_SCALE + 64;
// total ~= 60.6 MiB (proven ws >= 101.6 MiB from rounds 1-4)

// ---- qkv: x (NCHW fp32) -> q_row/k_row/v_row f16, computed once ----
__global__ __launch_bounds__(256,4) void qkv_kernel(
    const float* __restrict__ x,
    const float* __restrict__ wq, const float* __restrict__ bq,
    const float* __restrict__ wk, const float* __restrict__ bk,
    const float* __restrict__ wv, const float* __restrict__ bv,
    _Float16* __restrict__ qrow, _Float16* __restrict__ krow,
    _Float16* __restrict__ vrow)
{
    __shared__ __align__(16) float xs[128][68];   // 34816 B; later overlaid by vstage+qkstage
    const int tid = threadIdx.x;
    const int w0 = blockIdx.x * 32;
    const int h0 = blockIdx.y * 4;
    const int b  = blockIdx.z;

    const float* xb = x + (size_t)b*C_*HW_;
    for (int i = tid; i < 2048; i += 256) {       // 64c x 4h x 8 w-quads
        int c = i >> 5, hh = (i >> 3) & 3, w4 = i & 7;
        float4 v = *(const float4*)(xb + (size_t)c*HW_ + (size_t)(h0+hh)*W_ + w0 + w4*4);
        int pix = hh*32 + w4*4;
        xs[pix+0][c] = v.x; xs[pix+1][c] = v.y; xs[pix+2][c] = v.z; xs[pix+3][c] = v.w;
    }
    __syncthreads();

    // V: thread = (c-pair, 16-pixel group); weights in regs; LDS reads broadcast
    float resv[32];
    {
        const int cp = tid & 31, pg = tid >> 5;
        const int c0 = 2*cp, g = c0 >> 4;
        float w0r[16], w1r[16];
        #pragma unroll
        for (int p = 0; p < 4; p++) {
            *(float4*)&w0r[4*p] = ((const float4*)(wv + c0*16))[p];
            *(float4*)&w1r[4*p] = ((const float4*)(wv + (c0+1)*16))[p];
        }
        const float b0 = bv[c0], b1 = bv[c0+1];
        #pragma unroll 4
        for (int i = 0; i < 16; i++) {
            int pix = pg*16 + i;
            const float4* xr = (const float4*)&xs[pix][g*16];
            resv[2*i]   = dot16(xr, w0r, b0);
            resv[2*i+1] = dot16(xr, w1r, b1);
        }
    }
    // QK: thread = (one of 16 outputs, 8-pixel group)
    float resqk[8];
    {
        const int out = tid & 15, pg = tid >> 4;
        const int cq = out & 7, g = cq >> 1;
        const float* wp = ((out < 8) ? wq : wk) + cq*16;
        const float bb = (out < 8) ? bq[cq] : bk[cq];
        float wr[16];
        #pragma unroll
        for (int p = 0; p < 4; p++) *(float4*)&wr[4*p] = ((const float4*)wp)[p];
        #pragma unroll
        for (int i = 0; i < 8; i++) {
            int pix = pg*8 + i;
            resqk[i] = dot16((const float4*)&xs[pix][g*16], wr, bb);
        }
    }
    __syncthreads();   // all xs reads done -> overlay

    unsigned* vs32 = (unsigned*)&xs[0][0];        // vstage [128 pix][32 c-pairs] dw
    unsigned* qk32 = vs32 + 4096;                 // qkstage [128 pix][8] dw (q0..3,k0..3)
    {
        const int cp = tid & 31, pg = tid >> 5;
        #pragma unroll
        for (int i = 0; i < 16; i++) {
            int pix = pg*16 + i;
            h2 p; p.x = (_Float16)resv[2*i]; p.y = (_Float16)resv[2*i+1];
            vs32[pix*32 + cp] = *(unsigned*)&p;
        }
    }
    {
        const int out = tid & 15, pg = tid >> 4;
        _Float16* qks = (_Float16*)qk32;
        #pragma unroll
        for (int i = 0; i < 8; i++) qks[(pg*8+i)*16 + out] = (_Float16)resqk[i];
    }
    __syncthreads();

    unsigned* vrow32 = (unsigned*)vrow;
    for (int i = tid; i < 4096; i += 256) {
        int pix = i >> 5, cp = i & 31;
        size_t bp = ((size_t)b*H_ + h0 + (pix>>5))*W_ + w0 + (pix & 31);
        vrow32[bp*32 + cp] = vs32[i];
    }
    unsigned* qrow32 = (unsigned*)qrow;
    unsigned* krow32 = (unsigned*)krow;
    for (int i = tid; i < 1024; i += 256) {
        int pix = i >> 3, part = i & 7;
        size_t bp = ((size_t)b*H_ + h0 + (pix>>5))*W_ + w0 + (pix & 31);
        unsigned val = qk32[pix*8 + part];
        if (part < 4) qrow32[bp*4 + part]     = val;
        else          krow32[bp*4 + part - 4] = val;
    }
}

// ---- pass A: per (b,w) column — H-attention (diag masked) ----
__global__ __launch_bounds__(256,4) void passA_kernel(
    const _Float16* __restrict__ qrow, const _Float16* __restrict__ krow,
    const _Float16* __restrict__ vrow,
    _Float16* __restrict__ outH, float* __restrict__ mH, float* __restrict__ sH)
{
    __shared__ __align__(16) h2 v2[64][84];          // vT[c][j-pair]
    __shared__ __align__(16) _Float16 q2h[160][8];
    __shared__ __align__(16) _Float16 k2h[160][8];
    __shared__ __align__(16) h2 Pt[32][84];

    const int tid = threadIdx.x;
    const int b = blockIdx.x / W_;
    const int w = blockIdx.x % W_;

    if (tid < 160) {
        size_t bp = ((size_t)b*H_ + tid)*W_ + w;
        *(int4*)&q2h[tid][0] = *(const int4*)(qrow + bp*8);
        *(int4*)&k2h[tid][0] = *(const int4*)(krow + bp*8);
    }
    {
        const unsigned* vr32 = (const unsigned*)vrow;
        const int cp = tid & 31, hp0 = tid >> 5;
        #pragma unroll 2
        for (int it = 0; it < 10; it++) {
            int hp = hp0 + 8*it;
            size_t bp0 = (size_t)b*HW_ + (size_t)(2*hp)*W_ + w;
            unsigned u0 = vr32[bp0*32 + cp];
            unsigned u1 = vr32[(bp0 + W_)*32 + cp];
            unsigned e  = __builtin_amdgcn_perm(u1, u0, 0x05040100);
            unsigned o  = __builtin_amdgcn_perm(u1, u0, 0x07060302);
            *(unsigned*)&v2[2*cp][hp]   = e;
            *(unsigned*)&v2[2*cp+1][hp] = o;
        }
    }
    __syncthreads();

    const int u    = tid & 7;
    const int wl   = tid >> 3;
    const int lane = tid & 63;
    const int wid  = tid >> 6;
    const int cM   = wid*16 + (lane & 15);
    const int m_   = lane & 15;
    const int dq   = lane >> 4;

    for (int t = 0; t < 5; t++) {
        const int qh = t*32 + wl;
        H8u qr; qr.v = *(const h8*)&q2h[qh][0];
        float ev[20];
        float mloc = -1e30f;
        #pragma unroll 2
        for (int p = 0; p < 10; p++) {
            int j0 = 2*(u + 8*p);
            H8u ka; ka.v = *(const h8*)&k2h[j0][0];
            H8u kb; kb.v = *(const h8*)&k2h[j0+1][0];
            float e0 = 0.f, e1 = 0.f;
            #pragma unroll
            for (int i = 0; i < 4; i++) {
                e0 = fdot2(qr.h[i], ka.h[i], e0);
                e1 = fdot2(qr.h[i], kb.h[i], e1);
            }
            ev[2*p] = e0; ev[2*p+1] = e1;
            if (j0   != qh) mloc = fmaxf(mloc, e0);
            if (j0+1 != qh) mloc = fmaxf(mloc, e1);
        }
        mloc = fmaxf(mloc, __shfl_xor(mloc, 1));
        mloc = fmaxf(mloc, __shfl_xor(mloc, 2));
        mloc = fmaxf(mloc, __shfl_xor(mloc, 4));
        float sloc = 0.f;
        #pragma unroll
        for (int p = 0; p < 10; p++) {
            int j0 = 2*(u + 8*p);
            float p0 = (j0   == qh) ? 0.f : __expf(ev[2*p]   - mloc);
            float p1 = (j0+1 == qh) ? 0.f : __expf(ev[2*p+1] - mloc);
            sloc += p0 + p1;
            h2 pp; pp.x = (_Float16)p0; pp.y = (_Float16)p1;
            Pt[wl][u + 8*p] = pp;
        }
        sloc += __shfl_xor(sloc, 1);
        sloc += __shfl_xor(sloc, 2);
        sloc += __shfl_xor(sloc, 4);
        if (u == 0) {
            mH[((size_t)b*W_ + w)*H_ + qh] = mloc;
            sH[((size_t)b*W_ + w)*H_ + qh] = sloc;
        }
        __syncthreads();

        f4v acc0 = {0.f,0.f,0.f,0.f}, acc1 = {0.f,0.f,0.f,0.f};
        #pragma unroll
        for (int kt = 0; kt < 5; kt++) {
            const int off = 64*kt + 16*dq;
            h8 bfr = *(const h8*)((const char*)&v2[cM][0] + off);
            h8 a0  = *(const h8*)((const char*)&Pt[m_][0] + off);
            h8 a1  = *(const h8*)((const char*)&Pt[16 + m_][0] + off);
            acc0 = __builtin_amdgcn_mfma_f32_16x16x32_f16(a0, bfr, acc0, 0, 0, 0);
            acc1 = __builtin_amdgcn_mfma_f32_16x16x32_f16(a1, bfr, acc1, 0, 0, 0);
        }
        #pragma unroll
        for (int r = 0; r < 4; r++) {
            int r0 = t*32 + dq*4 + r;       // C/D: col=lane&15, row=(lane>>4)*4+reg
            outH[(((size_t)b*H_ + r0     )*W_ + w)*64 + cM] = (_Float16)acc0[r];
            outH[(((size_t)b*H_ + r0 + 16)*W_ + w)*64 + cM] = (_Float16)acc1[r];
        }
        __syncthreads();                    // Pt reused next tile
    }
}

// ---- pass B: per (b,h) row — W-attention + merge + w1d conv + BN partials ----
__global__ __launch_bounds__(256,4) void passB_kernel(
    const _Float16* __restrict__ qrow, const _Float16* __restrict__ krow,
    const _Float16* vrow,                 // aliases o16 — no restrict
    const float* __restrict__ gamma, const float* __restrict__ w1d,
    const _Float16* __restrict__ outH, const float* __restrict__ mH, const float* __restrict__ sH,
    _Float16* o16, float* __restrict__ bnsum, float* __restrict__ bnsq)
{
    __shared__ __align__(16) h2 v2[64][84];
    __shared__ __align__(16) _Float16 q2h[160][8];
    __shared__ __align__(16) _Float16 k2h[160][8];
    __shared__ __align__(16) h2 Pt[32][84];          // overlaid by stage[32][68] f32
    __shared__ float fHs[32], fWs[32];

    const int tid = threadIdx.x;
    const int b = blockIdx.x / H_;
    const int h = blockIdx.x % H_;
    const float gam = gamma[0];

    const int lane = tid & 63;
    const int wid  = tid >> 6;
    const int cM   = wid*16 + (lane & 15);
    const int m_   = lane & 15;
    const int dq   = lane >> 4;

    float w1dr[16];
    #pragma unroll
    for (int p = 0; p < 4; p++) *(float4*)&w1dr[4*p] = ((const float4*)(w1d + cM*16))[p];

    const size_t rowbase = ((size_t)b*H_ + h)*W_;
    if (tid < 160) {
        size_t bp = rowbase + tid;
        *(int4*)&q2h[tid][0] = *(const int4*)(qrow + bp*8);
        *(int4*)&k2h[tid][0] = *(const int4*)(krow + bp*8);
    }
    {
        const unsigned* vr32 = (const unsigned*)vrow;
        const int cp = tid & 31, wp0 = tid >> 5;
        #pragma unroll 2
        for (int it = 0; it < 10; it++) {
            int wp = wp0 + 8*it;
            size_t bp0 = rowbase + 2*wp;
            unsigned u0 = vr32[bp0*32 + cp];
            unsigned u1 = vr32[(bp0 + 1)*32 + cp];
            unsigned e  = __builtin_amdgcn_perm(u1, u0, 0x05040100);
            unsigned o  = __builtin_amdgcn_perm(u1, u0, 0x07060302);
            *(unsigned*)&v2[2*cp][wp]   = e;
            *(unsigned*)&v2[2*cp+1][wp] = o;
        }
    }
    __syncthreads();

    const int u  = tid & 7;
    const int wl = tid >> 3;
    float bnS = 0.f, bnS2 = 0.f;

    for (int t = 0; t < 5; t++) {
        // prefetch outH (f16) for this tile — covered by energy phase
        float oh0[4], oh1[4];
        #pragma unroll
        for (int r = 0; r < 4; r++) {
            int rw0 = t*32 + dq*4 + r;
            oh0[r] = (float)outH[(rowbase + rw0     )*64 + cM];
            oh1[r] = (float)outH[(rowbase + rw0 + 16)*64 + cM];
        }

        const int qw = t*32 + wl;
        H8u qr; qr.v = *(const h8*)&q2h[qw][0];
        float ev[20];
        float mloc = -1e30f;
        #pragma unroll 2
        for (int p = 0; p < 10; p++) {
            int j0 = 2*(u + 8*p);
            H8u ka; ka.v = *(const h8*)&k2h[j0][0];
            H8u kb; kb.v = *(const h8*)&k2h[j0+1][0];
            float e0 = 0.f, e1 = 0.f;
            #pragma unroll
            for (int i = 0; i < 4; i++) {
                e0 = fdot2(qr.h[i], ka.h[i], e0);
                e1 = fdot2(qr.h[i], kb.h[i], e1);
            }
            ev[2*p] = e0; ev[2*p+1] = e1;
            mloc = fmaxf(mloc, e0);
            mloc = fmaxf(mloc, e1);
        }
        mloc = fmaxf(mloc, __shfl_xor(mloc, 1));
        mloc = fmaxf(mloc, __shfl_xor(mloc, 2));
        mloc = fmaxf(mloc, __shfl_xor(mloc, 4));
        float sloc = 0.f;
        #pragma unroll
        for (int p = 0; p < 10; p++) {
            float p0 = __expf(ev[2*p]   - mloc);
            float p1 = __expf(ev[2*p+1] - mloc);
            sloc += p0 + p1;
            h2 pp; pp.x = (_Float16)p0; pp.y = (_Float16)p1;
            Pt[wl][u + 8*p] = pp;
        }
        sloc += __shfl_xor(sloc, 1);
        sloc += __shfl_xor(sloc, 2);
        sloc += __shfl_xor(sloc, 4);
        if (u == 0) {
            float mHv = mH[((size_t)b*W_ + qw)*H_ + h];
            float sHv = sH[((size_t)b*W_ + qw)*H_ + h];
            float M   = fmaxf(mHv, mloc);
            float eH  = __expf(mHv - M), eW = __expf(mloc - M);
            float inv = gam / (sHv*eH + sloc*eW);
            fHs[wl] = eH * inv;
            fWs[wl] = eW * inv;
        }
        __syncthreads();                               // b1: Pt/fHs ready

        f4v acc0 = {0.f,0.f,0.f,0.f}, acc1 = {0.f,0.f,0.f,0.f};
        #pragma unroll
        for (int kt = 0; kt < 5; kt++) {
            const int off = 64*kt + 16*dq;
            h8 bfr = *(const h8*)((const char*)&v2[cM][0] + off);
            h8 a0  = *(const h8*)((const char*)&Pt[m_][0] + off);
            h8 a1  = *(const h8*)((const char*)&Pt[16 + m_][0] + off);
            acc0 = __builtin_amdgcn_mfma_f32_16x16x32_f16(a0, bfr, acc0, 0, 0, 0);
            acc1 = __builtin_amdgcn_mfma_f32_16x16x32_f16(a1, bfr, acc1, 0, 0, 0);
        }
        __syncthreads();                               // b2: Pt reads done -> overlay stage

        float* stage = (float*)&Pt[0][0];              // [32][68] f32 (8704 B <= 10752)
        #pragma unroll
        for (int r = 0; r < 4; r++) {
            int rl0 = dq*4 + r, rl1 = rl0 + 16;
            stage[rl0*68 + cM] = oh0[r]*fHs[rl0] + acc0[r]*fWs[rl0];
            stage[rl1*68 + cM] = oh1[r]*fHs[rl1] + acc1[r]*fWs[rl1];
        }
        // grouped w1d conv: wave wid reads exactly the 16 cols it wrote (wave-local)
        #pragma unroll
        for (int r = 0; r < 4; r++) {
            #pragma unroll
            for (int mt = 0; mt < 2; mt++) {
                int rl = dq*4 + r + 16*mt;
                int rw = t*32 + rl;
                const float4* sp = (const float4*)&stage[rl*68 + 16*wid];
                float o = 0.f;
                #pragma unroll
                for (int p = 0; p < 4; p++) {
                    float4 sv = sp[p];
                    o += sv.x*w1dr[4*p] + sv.y*w1dr[4*p+1] + sv.z*w1dr[4*p+2] + sv.w*w1dr[4*p+3];
                }
                o16[(rowbase + rw)*64 + cM] = (_Float16)o;
                bnS  += o;
                bnS2 += o*o;
            }
        }
        __syncthreads();                               // b3: stage reads done before next Pt
    }
    bnS  += __shfl_xor(bnS, 16);  bnS  += __shfl_xor(bnS, 32);
    bnS2 += __shfl_xor(bnS2, 16); bnS2 += __shfl_xor(bnS2, 32);
    if (dq == 0) {
        atomicAdd(&bnsum[cM], bnS);
        atomicAdd(&bnsq[cM],  bnS2);
    }
}

// ---- BN finalize ----
__global__ void bnfin_kernel(const float* __restrict__ sum, const float* __restrict__ sq,
                             const float* __restrict__ bn_w, const float* __restrict__ bn_b,
                             float* __restrict__ scale, float* __restrict__ shift)
{
    int c = threadIdx.x;
    if (c < C_) {
        const float cnt = (float)(B_*H_*W_);
        float mean = sum[c] / cnt;
        float var  = sq[c] / cnt - mean*mean;
        float istd = rsqrtf(var + 1e-5f);
        float scl  = bn_w[c] * istd;
        scale[c] = scl;
        shift[c] = bn_b[c] - mean*scl;
    }
}

// ---- final: normalize + residual + relu, pixel-major f16 -> NCHW fp32 ----
__global__ __launch_bounds__(256) void final_kernel(
    const float* __restrict__ x, const _Float16* __restrict__ o16,
    const float* __restrict__ scale, const float* __restrict__ shift,
    float* __restrict__ out)
{
    __shared__ _Float16 olds[160*66];
    __shared__ float sc[64], sh[64];
    const int tid = threadIdx.x;
    const int b = blockIdx.x / H_, h = blockIdx.x % H_;
    if (tid < 64) { sc[tid] = scale[tid]; sh[tid] = shift[tid]; }
    const unsigned* op = (const unsigned*)(o16 + ((size_t)b*H_ + h)*W_*64);
    unsigned* ol32 = (unsigned*)olds;
    for (int i = tid; i < 5120; i += 256) {
        int w = i >> 5, c2 = i & 31;
        ol32[w*33 + c2] = op[i];
    }
    __syncthreads();
    const float* xr = x   + (size_t)b*C_*HW_ + (size_t)h*W_;
    float*       ob = out + (size_t)b*C_*HW_ + (size_t)h*W_;
    for (int i = tid; i < 64*160; i += 256) {
        int c = i / 160, w = i - c*160;
        float v = (float)olds[w*66 + c] * sc[c] + sh[c] + xr[(size_t)c*HW_ + w];
        ob[(size_t)c*HW_ + w] = fmaxf(v, 0.f);
    }
}

extern "C" void kernel_launch(void* const* d_in, const int* in_sizes, int n_in,
                              void* d_out, int out_size, void* d_ws, size_t ws_size,
                              hipStream_t stream)
{
    (void)in_sizes; (void)n_in; (void)out_size; (void)ws_size;
    const float* x     = (const float*)d_in[0];
    const float* wq    = (const float*)d_in[1];
    const float* bq    = (const float*)d_in[2];
    const float* wk    = (const float*)d_in[3];
    const float* bk    = (const float*)d_in[4];
    const float* wv    = (const float*)d_in[5];
    const float* bv    = (const float*)d_in[6];
    const float* gamma = (const float*)d_in[7];
    const float* w1d   = (const float*)d_in[8];
    const float* bn_w  = (const float*)d_in[9];
    const float* bn_b  = (const float*)d_in[10];

    float* ws = (float*)d_ws;
    _Float16* outH16 = (_Float16*)(ws + OFF_OUTH);
    _Float16* vrow   = (_Float16*)(ws + OFF_VROW);
    _Float16* qrow   = (_Float16*)(ws + OFF_QROW);
    _Float16* krow   = (_Float16*)(ws + OFF_KROW);
    float* mH    = ws + OFF_MH;
    float* sH    = ws + OFF_SH;
    float* bnsum = ws + OFF_BNSUM;
    float* bnsq  = ws + OFF_BNSQ;
    float* scale = ws + OFF_SCALE;
    float* shift = ws + OFF_SHIFT;
    _Float16* o16 = vrow;   // alias: each passB block overwrites only the row it consumed

    hipMemsetAsync(bnsum, 0, 128*sizeof(float), stream);

    dim3 qgrid(W_/32, H_/4, B_);
    qkv_kernel<<<qgrid, 256, 0, stream>>>(x, wq, bq, wk, bk, wv, bv, qrow, krow, vrow);
    passA_kernel<<<B_*W_, 256, 0, stream>>>(qrow, krow, vrow, outH16, mH, sH);
    passB_kernel<<<B_*H_, 256, 0, stream>>>(qrow, krow, vrow, gamma, w1d,
                                            outH16, mH, sH, o16, bnsum, bnsq);
    bnfin_kernel<<<1, 64, 0, stream>>>(bnsum, bnsq, bn_w, bn_b, scale, shift);
    final_kernel<<<B_*H_, 256, 0, stream>>>(x, o16, scale, shift, (float*)d_out);
}

// Round 6
// 243.979 us; speedup vs baseline: 3.2522x; 1.0351x over previous
//
#include <hip/hip_runtime.h>
#include <math.h>

#define B_ 8
#define C_ 64
#define H_ 160
#define W_ 160
#define HW_ (H_*W_)

typedef _Float16 h2 __attribute__((ext_vector_type(2)));
typedef _Float16 h8 __attribute__((ext_vector_type(8)));
typedef float f4v __attribute__((ext_vector_type(4)));
union H8u { h8 v; h2 h[4]; };

__device__ inline float fdot2(h2 a, h2 b, float c) {
    return __builtin_amdgcn_fdot2(a, b, c, false);
}
__device__ inline float dot16(const float4* xr, const float* wr, float acc) {
    float4 a = xr[0], b = xr[1], c = xr[2], d = xr[3];
    acc += a.x*wr[0]  + a.y*wr[1]  + a.z*wr[2]  + a.w*wr[3];
    acc += b.x*wr[4]  + b.y*wr[5]  + b.z*wr[6]  + b.w*wr[7];
    acc += c.x*wr[8]  + c.y*wr[9]  + c.z*wr[10] + c.w*wr[11];
    acc += d.x*wr[12] + d.y*wr[13] + d.z*wr[14] + d.w*wr[15];
    return acc;
}

static constexpr size_t N_PIX  = (size_t)B_*H_*W_;       // 204800
static constexpr size_t N_FULL = (size_t)B_*H_*W_*C_;    // 13107200
// ws (float units):
static constexpr size_t OFF_OUTH  = 0;                       // outH f16 [b][h][w][c]
static constexpr size_t OFF_VROW  = N_FULL/2;                // v_row f16 [b][h][w][c]; o16 aliases
static constexpr size_t OFF_QROW  = OFF_VROW + N_FULL/2;     // q_row f16 [b][h][w][8]
static constexpr size_t OFF_KROW  = OFF_QROW + N_PIX*4;
static constexpr size_t OFF_MH    = OFF_KROW + N_PIX*4;      // fp32 [b][w][h]
static constexpr size_t OFF_SH    = OFF_MH + N_PIX;
static constexpr size_t OFF_BNSUM = OFF_SH + N_PIX;
static constexpr size_t OFF_BNSQ  = OFF_BNSUM + 64;

// ---- qkv: x (NCHW fp32) -> q_row/k_row/v_row f16, computed once ----
__global__ __launch_bounds__(256,4) void qkv_kernel(
    const float* __restrict__ x,
    const float* __restrict__ wq, const float* __restrict__ bq,
    const float* __restrict__ wk, const float* __restrict__ bk,
    const float* __restrict__ wv, const float* __restrict__ bv,
    _Float16* __restrict__ qrow, _Float16* __restrict__ krow,
    _Float16* __restrict__ vrow)
{
    __shared__ __align__(16) float xs[128][68];   // later overlaid by vstage+qkstage
    const int tid = threadIdx.x;
    const int w0 = blockIdx.x * 32;
    const int h0 = blockIdx.y * 4;
    const int b  = blockIdx.z;

    const float* xb = x + (size_t)b*C_*HW_;
    // mapping: per wave-instruction lanes span 8 channels x 8 w-quads -> 4-way LDS banks
    for (int i = tid; i < 2048; i += 256) {
        int w4 = i & 7;
        int c  = ((i >> 3) & 7) | (((i >> 6) & 7) << 3);
        int hh = i >> 9;
        float4 v = *(const float4*)(xb + (size_t)c*HW_ + (size_t)(h0+hh)*W_ + w0 + w4*4);
        int pix = hh*32 + w4*4;
        xs[pix+0][c] = v.x; xs[pix+1][c] = v.y; xs[pix+2][c] = v.z; xs[pix+3][c] = v.w;
    }
    __syncthreads();

    // V: thread = (c-pair, 16-pixel group); weights in regs; LDS reads broadcast
    float resv[32];
    {
        const int cp = tid & 31, pg = tid >> 5;
        const int c0 = 2*cp, g = c0 >> 4;
        float w0r[16], w1r[16];
        #pragma unroll
        for (int p = 0; p < 4; p++) {
            *(float4*)&w0r[4*p] = ((const float4*)(wv + c0*16))[p];
            *(float4*)&w1r[4*p] = ((const float4*)(wv + (c0+1)*16))[p];
        }
        const float b0 = bv[c0], b1 = bv[c0+1];
        #pragma unroll 4
        for (int i = 0; i < 16; i++) {
            int pix = pg*16 + i;
            const float4* xr = (const float4*)&xs[pix][g*16];
            resv[2*i]   = dot16(xr, w0r, b0);
            resv[2*i+1] = dot16(xr, w1r, b1);
        }
    }
    // QK: thread = (one of 16 outputs, 8-pixel group)
    float resqk[8];
    {
        const int out = tid & 15, pg = tid >> 4;
        const int cq = out & 7, g = cq >> 1;
        const float* wp = ((out < 8) ? wq : wk) + cq*16;
        const float bb = (out < 8) ? bq[cq] : bk[cq];
        float wr[16];
        #pragma unroll
        for (int p = 0; p < 4; p++) *(float4*)&wr[4*p] = ((const float4*)wp)[p];
        #pragma unroll
        for (int i = 0; i < 8; i++) {
            int pix = pg*8 + i;
            resqk[i] = dot16((const float4*)&xs[pix][g*16], wr, bb);
        }
    }
    __syncthreads();   // all xs reads done -> overlay

    unsigned* vs32 = (unsigned*)&xs[0][0];        // vstage [128 pix][32 c-pairs] dw
    unsigned* qk32 = vs32 + 4096;                 // qkstage [128 pix][8] dw
    {
        const int cp = tid & 31, pg = tid >> 5;
        #pragma unroll
        for (int i = 0; i < 16; i++) {
            int pix = pg*16 + i;
            h2 p; p.x = (_Float16)resv[2*i]; p.y = (_Float16)resv[2*i+1];
            vs32[pix*32 + cp] = *(unsigned*)&p;
        }
    }
    {
        const int out = tid & 15, pg = tid >> 4;
        _Float16* qks = (_Float16*)qk32;
        #pragma unroll
        for (int i = 0; i < 8; i++) qks[(pg*8+i)*16 + out] = (_Float16)resqk[i];
    }
    __syncthreads();

    unsigned* vrow32 = (unsigned*)vrow;
    for (int i = tid; i < 4096; i += 256) {
        int pix = i >> 5, cp = i & 31;
        size_t bp = ((size_t)b*H_ + h0 + (pix>>5))*W_ + w0 + (pix & 31);
        vrow32[bp*32 + cp] = vs32[i];
    }
    unsigned* qrow32 = (unsigned*)qrow;
    unsigned* krow32 = (unsigned*)krow;
    for (int i = tid; i < 1024; i += 256) {
        int pix = i >> 3, part = i & 7;
        size_t bp = ((size_t)b*H_ + h0 + (pix>>5))*W_ + w0 + (pix & 31);
        unsigned val = qk32[pix*8 + part];
        if (part < 4) qrow32[bp*4 + part]     = val;
        else          krow32[bp*4 + part - 4] = val;
    }
}

// ---- pass A: per (b,w) column — H-attention (diag masked) ----
// LDS in MFMA-fragment order: v2s/Pts [kt][dq][row][8]
__global__ __launch_bounds__(256,4) void passA_kernel(
    const _Float16* __restrict__ qrow, const _Float16* __restrict__ krow,
    const _Float16* __restrict__ vrow,
    _Float16* __restrict__ outH, float* __restrict__ mH, float* __restrict__ sH)
{
    __shared__ __align__(16) _Float16 v2s[5*4*64*8];   // 20480 B
    __shared__ __align__(16) _Float16 Pts[5*4*32*8];   // 10240 B
    __shared__ __align__(16) _Float16 q2h[160][8];
    __shared__ __align__(16) _Float16 k2h[160][8];

    const int tid = threadIdx.x;
    const int b = blockIdx.x / W_;
    const int w = blockIdx.x % W_;

    if (tid < 160) {
        size_t bp = ((size_t)b*H_ + tid)*W_ + w;
        *(int4*)&q2h[tid][0] = *(const int4*)(qrow + bp*8);
        *(int4*)&k2h[tid][0] = *(const int4*)(krow + bp*8);
    }
    {
        const unsigned* vr32 = (const unsigned*)vrow;
        const int cp = tid & 31, hp0 = tid >> 5;
        #pragma unroll 2
        for (int it = 0; it < 10; it++) {
            int hp = hp0 + 8*it;                       // j-pair index
            int kt = hp >> 4, dqv = (hp >> 2) & 3, jj = 2*(hp & 3);
            size_t bp0 = ((size_t)b*H_ + 2*hp)*W_ + w;
            unsigned u0 = vr32[bp0*32 + cp];
            unsigned u1 = vr32[(bp0 + W_)*32 + cp];
            unsigned e  = __builtin_amdgcn_perm(u1, u0, 0x05040100);
            unsigned o  = __builtin_amdgcn_perm(u1, u0, 0x07060302);
            int base = ((kt*4 + dqv)*64 + 2*cp)*8 + jj;
            *(unsigned*)&v2s[base]     = e;
            *(unsigned*)&v2s[base + 8] = o;
        }
    }
    __syncthreads();

    const int u    = tid & 7;
    const int wl   = tid >> 3;
    const int lane = tid & 63;
    const int wid  = tid >> 6;
    const int cM   = wid*16 + (lane & 15);
    const int m_   = lane & 15;
    const int dq   = lane >> 4;

    for (int t = 0; t < 5; t++) {
        const int qh = t*32 + wl;
        H8u qr; qr.v = *(const h8*)&q2h[qh][0];
        float ev[20];
        float mloc = -1e30f;
        #pragma unroll 2
        for (int p = 0; p < 10; p++) {
            int j0 = 2*u + 16*p;
            H8u ka; ka.v = *(const h8*)&k2h[j0][0];
            H8u kb; kb.v = *(const h8*)&k2h[j0+1][0];
            float e0 = 0.f, e1 = 0.f;
            #pragma unroll
            for (int i = 0; i < 4; i++) {
                e0 = fdot2(qr.h[i], ka.h[i], e0);
                e1 = fdot2(qr.h[i], kb.h[i], e1);
            }
            ev[2*p] = e0; ev[2*p+1] = e1;
            if (j0   != qh) mloc = fmaxf(mloc, e0);
            if (j0+1 != qh) mloc = fmaxf(mloc, e1);
        }
        mloc = fmaxf(mloc, __shfl_xor(mloc, 1));
        mloc = fmaxf(mloc, __shfl_xor(mloc, 2));
        mloc = fmaxf(mloc, __shfl_xor(mloc, 4));
        float sloc = 0.f;
        #pragma unroll
        for (int p = 0; p < 10; p++) {
            int j0 = 2*u + 16*p;
            float p0 = (j0   == qh) ? 0.f : __expf(ev[2*p]   - mloc);
            float p1 = (j0+1 == qh) ? 0.f : __expf(ev[2*p+1] - mloc);
            sloc += p0 + p1;
            h2 pp; pp.x = (_Float16)p0; pp.y = (_Float16)p1;
            int idx = (((p>>1)*4 + (u>>2) + 2*(p&1))*32 + wl)*8 + 2*(u&3);
            *(unsigned*)&Pts[idx] = *(unsigned*)&pp;
        }
        sloc += __shfl_xor(sloc, 1);
        sloc += __shfl_xor(sloc, 2);
        sloc += __shfl_xor(sloc, 4);
        if (u == 0) {
            mH[((size_t)b*W_ + w)*H_ + qh] = mloc;
            sH[((size_t)b*W_ + w)*H_ + qh] = sloc;
        }
        __syncthreads();                                   // b1: Pts ready

        f4v acc0 = {0.f,0.f,0.f,0.f}, acc1 = {0.f,0.f,0.f,0.f};
        #pragma unroll
        for (int kt = 0; kt < 5; kt++) {
            h8 bfr = *(const h8*)&v2s[((kt*4 + dq)*64 + cM)*8];
            h8 a0  = *(const h8*)&Pts[((kt*4 + dq)*32 + m_)*8];
            h8 a1  = *(const h8*)&Pts[((kt*4 + dq)*32 + 16 + m_)*8];
            acc0 = __builtin_amdgcn_mfma_f32_16x16x32_f16(a0, bfr, acc0, 0, 0, 0);
            acc1 = __builtin_amdgcn_mfma_f32_16x16x32_f16(a1, bfr, acc1, 0, 0, 0);
        }
        #pragma unroll
        for (int r = 0; r < 4; r++) {
            int r0 = t*32 + dq*4 + r;       // C/D: col=lane&15, row=(lane>>4)*4+reg
            outH[(((size_t)b*H_ + r0     )*W_ + w)*64 + cM] = (_Float16)acc0[r];
            outH[(((size_t)b*H_ + r0 + 16)*W_ + w)*64 + cM] = (_Float16)acc1[r];
        }
        __syncthreads();                                   // b2: Pts reads done
    }
}

// ---- pass B: per (b,h) row — W-attention + merge + w1d conv + BN partials ----
__global__ __launch_bounds__(256,4) void passB_kernel(
    const _Float16* __restrict__ qrow, const _Float16* __restrict__ krow,
    const _Float16* vrow,                 // aliases o16 — no restrict
    const float* __restrict__ gamma, const float* __restrict__ w1d,
    const _Float16* __restrict__ outH, const float* __restrict__ mH, const float* __restrict__ sH,
    _Float16* o16, float* __restrict__ bnsum, float* __restrict__ bnsq)
{
    __shared__ __align__(16) _Float16 v2s[5*4*64*8];     // 20480 B
    __shared__ __align__(16) _Float16 Pts[5*4*32*8];     // 10240 B
    __shared__ __align__(16) _Float16 q2h[160][8];
    __shared__ __align__(16) _Float16 k2h[160][8];
    __shared__ __align__(16) _Float16 stageh[4*32*18];   // 4608 B, wave-private stripes
    __shared__ float fHs[32], fWs[32];
    // total 40704 B -> 4 blocks/CU

    const int tid = threadIdx.x;
    const int b = blockIdx.x / H_;
    const int h = blockIdx.x % H_;
    const float gam = gamma[0];

    const int lane = tid & 63;
    const int wid  = tid >> 6;
    const int cM   = wid*16 + (lane & 15);
    const int m_   = lane & 15;
    const int dq   = lane >> 4;

    // w1d as f16 pairs in regs
    h2 w1h[8];
    #pragma unroll
    for (int p = 0; p < 8; p++) {
        float2 wpair = ((const float2*)(w1d + cM*16))[p];
        h2 wp; wp.x = (_Float16)wpair.x; wp.y = (_Float16)wpair.y;
        w1h[p] = wp;
    }

    const size_t rowbase = ((size_t)b*H_ + h)*W_;
    if (tid < 160) {
        size_t bp = rowbase + tid;
        *(int4*)&q2h[tid][0] = *(const int4*)(qrow + bp*8);
        *(int4*)&k2h[tid][0] = *(const int4*)(krow + bp*8);
    }
    {
        const unsigned* vr32 = (const unsigned*)vrow;
        const int cp = tid & 31, wp0 = tid >> 5;
        #pragma unroll 2
        for (int it = 0; it < 10; it++) {
            int wp = wp0 + 8*it;
            int kt = wp >> 4, dqv = (wp >> 2) & 3, jj = 2*(wp & 3);
            size_t bp0 = rowbase + 2*wp;
            unsigned u0 = vr32[bp0*32 + cp];
            unsigned u1 = vr32[(bp0 + 1)*32 + cp];
            unsigned e  = __builtin_amdgcn_perm(u1, u0, 0x05040100);
            unsigned o  = __builtin_amdgcn_perm(u1, u0, 0x07060302);
            int base = ((kt*4 + dqv)*64 + 2*cp)*8 + jj;
            *(unsigned*)&v2s[base]     = e;
            *(unsigned*)&v2s[base + 8] = o;
        }
    }
    __syncthreads();

    const int u  = tid & 7;
    const int wl = tid >> 3;
    float bnS = 0.f, bnS2 = 0.f;

    for (int t = 0; t < 5; t++) {
        // prefetch outH (f16) for this tile — covered by energy phase
        float oh0[4], oh1[4];
        #pragma unroll
        for (int r = 0; r < 4; r++) {
            int rw0 = t*32 + dq*4 + r;
            oh0[r] = (float)outH[(rowbase + rw0     )*64 + cM];
            oh1[r] = (float)outH[(rowbase + rw0 + 16)*64 + cM];
        }

        const int qw = t*32 + wl;
        H8u qr; qr.v = *(const h8*)&q2h[qw][0];
        float ev[20];
        float mloc = -1e30f;
        #pragma unroll 2
        for (int p = 0; p < 10; p++) {
            int j0 = 2*u + 16*p;
            H8u ka; ka.v = *(const h8*)&k2h[j0][0];
            H8u kb; kb.v = *(const h8*)&k2h[j0+1][0];
            float e0 = 0.f, e1 = 0.f;
            #pragma unroll
            for (int i = 0; i < 4; i++) {
                e0 = fdot2(qr.h[i], ka.h[i], e0);
                e1 = fdot2(qr.h[i], kb.h[i], e1);
            }
            ev[2*p] = e0; ev[2*p+1] = e1;
            mloc = fmaxf(mloc, e0);
            mloc = fmaxf(mloc, e1);
        }
        mloc = fmaxf(mloc, __shfl_xor(mloc, 1));
        mloc = fmaxf(mloc, __shfl_xor(mloc, 2));
        mloc = fmaxf(mloc, __shfl_xor(mloc, 4));
        float sloc = 0.f;
        #pragma unroll
        for (int p = 0; p < 10; p++) {
            float p0 = __expf(ev[2*p]   - mloc);
            float p1 = __expf(ev[2*p+1] - mloc);
            sloc += p0 + p1;
            h2 pp; pp.x = (_Float16)p0; pp.y = (_Float16)p1;
            int idx = (((p>>1)*4 + (u>>2) + 2*(p&1))*32 + wl)*8 + 2*(u&3);
            *(unsigned*)&Pts[idx] = *(unsigned*)&pp;
        }
        sloc += __shfl_xor(sloc, 1);
        sloc += __shfl_xor(sloc, 2);
        sloc += __shfl_xor(sloc, 4);
        if (u == 0) {
            float mHv = mH[((size_t)b*W_ + qw)*H_ + h];
            float sHv = sH[((size_t)b*W_ + qw)*H_ + h];
            float M   = fmaxf(mHv, mloc);
            float eH  = __expf(mHv - M), eW = __expf(mloc - M);
            float inv = gam / (sHv*eH + sloc*eW);
            fHs[wl] = eH * inv;
            fWs[wl] = eW * inv;
        }
        __syncthreads();                               // b1: Pts/fHs ready

        f4v acc0 = {0.f,0.f,0.f,0.f}, acc1 = {0.f,0.f,0.f,0.f};
        #pragma unroll
        for (int kt = 0; kt < 5; kt++) {
            h8 bfr = *(const h8*)&v2s[((kt*4 + dq)*64 + cM)*8];
            h8 a0  = *(const h8*)&Pts[((kt*4 + dq)*32 + m_)*8];
            h8 a1  = *(const h8*)&Pts[((kt*4 + dq)*32 + 16 + m_)*8];
            acc0 = __builtin_amdgcn_mfma_f32_16x16x32_f16(a0, bfr, acc0, 0, 0, 0);
            acc1 = __builtin_amdgcn_mfma_f32_16x16x32_f16(a1, bfr, acc1, 0, 0, 0);
        }
        // merge (gamma folded into fHs/fWs) -> wave-private stage, f16 — NO barrier needed
        _Float16* st = &stageh[wid*576];
        #pragma unroll
        for (int r = 0; r < 4; r++) {
            int rl0 = dq*4 + r, rl1 = rl0 + 16;
            st[rl0*18 + m_] = (_Float16)(oh0[r]*fHs[rl0] + acc0[r]*fWs[rl0]);
            st[rl1*18 + m_] = (_Float16)(oh1[r]*fHs[rl1] + acc1[r]*fWs[rl1]);
        }
        // grouped w1d conv: wave wid reads exactly the stripe it wrote (wave-local)
        #pragma unroll
        for (int r = 0; r < 4; r++) {
            #pragma unroll
            for (int mt = 0; mt < 2; mt++) {
                int rl = dq*4 + r + 16*mt;
                int rw = t*32 + rl;
                const h2* sp = (const h2*)&st[rl*18];
                float o = 0.f;
                #pragma unroll
                for (int p = 0; p < 8; p++) o = fdot2(sp[p], w1h[p], o);
                o16[(rowbase + rw)*64 + cM] = (_Float16)o;
                bnS  += o;
                bnS2 += o*o;
            }
        }
        __syncthreads();                               // b2: Pts reads done before next write
    }
    bnS  += __shfl_xor(bnS, 16);  bnS  += __shfl_xor(bnS, 32);
    bnS2 += __shfl_xor(bnS2, 16); bnS2 += __shfl_xor(bnS2, 32);
    if (dq == 0) {
        atomicAdd(&bnsum[cM], bnS);
        atomicAdd(&bnsq[cM],  bnS2);
    }
}

// ---- final: BN finalize (per-block, redundant) + normalize + residual + relu ----
__global__ __launch_bounds__(256) void final_kernel(
    const float* __restrict__ x, const _Float16* __restrict__ o16,
    const float* __restrict__ bnsum, const float* __restrict__ bnsq,
    const float* __restrict__ bn_w, const float* __restrict__ bn_b,
    float* __restrict__ out)
{
    __shared__ _Float16 olds[160*66];
    __shared__ float sc[64], sh[64];
    const int tid = threadIdx.x;
    const int b = blockIdx.x / H_, h = blockIdx.x % H_;
    if (tid < 64) {
        const float cnt = (float)(B_*H_*W_);
        float mean = bnsum[tid] / cnt;
        float var  = bnsq[tid] / cnt - mean*mean;
        float istd = rsqrtf(var + 1e-5f);
        float scl  = bn_w[tid] * istd;
        sc[tid] = scl;
        sh[tid] = bn_b[tid] - mean*scl;
    }
    const unsigned* op = (const unsigned*)(o16 + ((size_t)b*H_ + h)*W_*64);
    unsigned* ol32 = (unsigned*)olds;
    for (int i = tid; i < 5120; i += 256) {
        int w = i >> 5, c2 = i & 31;
        ol32[w*33 + c2] = op[i];
    }
    __syncthreads();
    const float* xr = x   + (size_t)b*C_*HW_ + (size_t)h*W_;
    float*       ob = out + (size_t)b*C_*HW_ + (size_t)h*W_;
    for (int i = tid; i < 64*160; i += 256) {
        int c = i / 160, w = i - c*160;
        float v = (float)olds[w*66 + c] * sc[c] + sh[c] + xr[(size_t)c*HW_ + w];
        ob[(size_t)c*HW_ + w] = fmaxf(v, 0.f);
    }
}

extern "C" void kernel_launch(void* const* d_in, const int* in_sizes, int n_in,
                              void* d_out, int out_size, void* d_ws, size_t ws_size,
                              hipStream_t stream)
{
    (void)in_sizes; (void)n_in; (void)out_size; (void)ws_size;
    const float* x     = (const float*)d_in[0];
    const float* wq    = (const float*)d_in[1];
    const float* bq    = (const float*)d_in[2];
    const float* wk    = (const float*)d_in[3];
    const float* bk    = (const float*)d_in[4];
    const float* wv    = (const float*)d_in[5];
    const float* bv    = (const float*)d_in[6];
    const float* gamma = (const float*)d_in[7];
    const float* w1d   = (const float*)d_in[8];
    const float* bn_w  = (const float*)d_in[9];
    const float* bn_b  = (const float*)d_in[10];

    float* ws = (float*)d_ws;
    _Float16* outH16 = (_Float16*)(ws + OFF_OUTH);
    _Float16* vrow   = (_Float16*)(ws + OFF_VROW);
    _Float16* qrow   = (_Float16*)(ws + OFF_QROW);
    _Float16* krow   = (_Float16*)(ws + OFF_KROW);
    float* mH    = ws + OFF_MH;
    float* sH    = ws + OFF_SH;
    float* bnsum = ws + OFF_BNSUM;
    float* bnsq  = ws + OFF_BNSQ;
    _Float16* o16 = vrow;   // alias: each passB block overwrites only the row it consumed

    hipMemsetAsync(bnsum, 0, 128*sizeof(float), stream);

    dim3 qgrid(W_/32, H_/4, B_);
    qkv_kernel<<<qgrid, 256, 0, stream>>>(x, wq, bq, wk, bk, wv, bv, qrow, krow, vrow);
    passA_kernel<<<B_*W_, 256, 0, stream>>>(qrow, krow, vrow, outH16, mH, sH);
    passB_kernel<<<B_*H_, 256, 0, stream>>>(qrow, krow, vrow, gamma, w1d,
                                            outH16, mH, sH, o16, bnsum, bnsq);
    final_kernel<<<B_*H_, 256, 0, stream>>>(x, o16, bnsum, bnsq, bn_w, bn_b, (float*)d_out);
}